// Round 5
// baseline (353.362 us; speedup 1.0000x reference)
//
#include <hip/hip_runtime.h>
#include <math.h>

// LESA block for MI355X. N=8, C=512, H=W=28 (HW=784), G=8, QKP=32, VP=64, BP=512.
// R5: (a) k_attn keeps logits in registers as packed fp16 pairs (Lp[13][2],
// 26 VGPRs) -- no fp16 LDS round-trip; phase 2 = unpack+exp+direct bf16 write.
// (b) GEMM kernels get 1-deep register prefetch of staging quanta + A-frag so
// the vmcnt wait is covered by the previous iteration's MFMA block.

typedef unsigned short u16;
typedef unsigned int u32;
typedef __bf16 bf16x8 __attribute__((ext_vector_type(8)));
typedef float f32x4 __attribute__((ext_vector_type(4)));

#define INVS 0.99999500003749968f  // 1/sqrt(1+1e-5)
#define MFMA16(a, b, c) __builtin_amdgcn_mfma_f32_16x16x32_bf16(a, b, c, 0, 0, 0)

__device__ inline u16 f2bf(float f) {
  u32 u = __builtin_bit_cast(u32, f);
  return (u16)((u + 0x7fffu + ((u >> 16) & 1u)) >> 16);
}
__device__ inline bf16x8 ld_bf8(const u16* p) {
  int4 v = *reinterpret_cast<const int4*>(p);
  return __builtin_bit_cast(bf16x8, v);
}
__device__ inline bf16x8 pack8(const u16 h[8]) {
  int4 v;
  v.x = (int)((u32)h[0] | ((u32)h[1] << 16));
  v.y = (int)((u32)h[2] | ((u32)h[3] << 16));
  v.z = (int)((u32)h[4] | ((u32)h[5] << 16));
  v.w = (int)((u32)h[6] | ((u32)h[7] << 16));
  return __builtin_bit_cast(bf16x8, v);
}
__device__ inline bf16x8 zero8() {
  int4 z = {0, 0, 0, 0};
  return __builtin_bit_cast(bf16x8, z);
}
__device__ inline float bpermf(float v, int srcl) {
  return __builtin_bit_cast(float,
      __builtin_amdgcn_ds_bpermute(srcl << 2, __builtin_bit_cast(int, v)));
}
__device__ inline u32 packh2(float a, float b) {
  u16 ha = __builtin_bit_cast(u16, (_Float16)a);
  u16 hb = __builtin_bit_cast(u16, (_Float16)b);
  return (u32)ha | ((u32)hb << 16);
}
__device__ inline float unpklo(u32 p) {
  return (float)__builtin_bit_cast(_Float16, (u16)(p & 0xffffu));
}
__device__ inline float unpkhi(u32 p) {
  return (float)__builtin_bit_cast(_Float16, (u16)(p >> 16));
}

// ---------------- prep: weight casts/permutes + relative tables ----------------
__global__ __launch_bounds__(256) void k_prep(
    const float* __restrict__ qkv_w, const float* __restrict__ xw2,
    const float* __restrict__ rw, const float* __restrict__ pw,
    const float* __restrict__ xw1, const float* __restrict__ rel,
    u16* __restrict__ Wq, u16* __restrict__ W2, u16* __restrict__ Wr,
    u16* __restrict__ Wp, u16* __restrict__ W1t, u16* __restrict__ relq,
    u16* __restrict__ relk, u16* __restrict__ relv) {
  int idx = blockIdx.x * 256 + threadIdx.x;
  if (idx < 524288) { Wq[idx] = f2bf(qkv_w[idx]); return; }
  idx -= 524288;
  if (idx < 262144) { W2[idx] = f2bf(xw2[idx]); return; }
  idx -= 262144;
  if (idx < 524288) { Wr[idx] = f2bf(rw[idx]); return; }
  idx -= 524288;
  if (idx < 262144) { Wp[idx] = f2bf(pw[idx]); return; }
  idx -= 262144;
  if (idx < 294912) {  // W1t[(g*9+k9)*64 + oc][ic] = xw1[g*64+oc][ic][kh][kw]
    int gk = idx >> 12, rem = idx & 4095, oc = rem >> 6, ic = rem & 63;
    int g = gk / 9, k9 = gk % 9;
    W1t[idx] = f2bf(xw1[(((g * 64 + oc) * 64) + ic) * 9 + k9]);
    return;
  }
  idx -= 294912;
  if (idx < 51200) {  // relq[t][c] = relative[c][t], t<1600 (pad 0)
    int t = idx >> 5, c = idx & 31;
    relq[idx] = (t < 1567) ? f2bf(rel[c * 1567 + t]) : (u16)0;
    return;
  }
  idx -= 51200;
  if (idx < 51200) {
    int t = idx >> 5, c = idx & 31;
    relk[idx] = (t < 1567) ? f2bf(rel[(32 + c) * 1567 + t]) : (u16)0;
    return;
  }
  idx -= 51200;
  if (idx < 102400) {  // relv[c][t] (c<64, t<1600 pad 0)
    int c = idx / 1600, t = idx % 1600;
    relv[idx] = (t < 1567) ? f2bf(rel[(64 + c) * 1567 + t]) : (u16)0;
    return;
  }
}

// ---------------- transpose x (b,512,784) f32 -> xT (b,784,512) bf16 ----------------
__global__ __launch_bounds__(256) void k_transpose(const float* __restrict__ x,
                                                   u16* __restrict__ xT) {
  const int b = blockIdx.z, c0 = blockIdx.y * 64, n0 = blockIdx.x * 32;
  const int tid = threadIdx.x;
  __shared__ __align__(16) u16 tl[64][36];
#pragma unroll
  for (int h = 0; h < 2; ++h) {
    int cl = (tid >> 3) + h * 32;
    int n4 = (tid & 7) * 4;
    float4 v = {0.f, 0.f, 0.f, 0.f};
    if (n0 + n4 + 3 < 784)
      v = *reinterpret_cast<const float4*>(x + ((size_t)b * 512 + c0 + cl) * 784 + n0 + n4);
    u32 lo = (u32)f2bf(v.x) | ((u32)f2bf(v.y) << 16);
    u32 hi = (u32)f2bf(v.z) | ((u32)f2bf(v.w) << 16);
    *reinterpret_cast<int2*>(&tl[cl][n4]) = make_int2((int)lo, (int)hi);
  }
  __syncthreads();
  int nl = tid >> 3, c8 = (tid & 7) * 8;
  if (n0 + nl < 784) {
    u16 h[8];
#pragma unroll
    for (int e = 0; e < 8; ++e) h[e] = tl[c8 + e][nl];
    *reinterpret_cast<int4*>(xT + ((size_t)b * 784 + n0 + nl) * 512 + c0 + c8) =
        __builtin_bit_cast(int4, pack8(h));
  }
}

// ---------------- qkv GEMM: (1024x512)@(512x784) + bn -> Q,K (j,c) / V (c,j) bf16 ----------------
__global__ __launch_bounds__(256) void k_gemm_qkv(
    const u16* __restrict__ W, const u16* __restrict__ xT,
    const float* __restrict__ gq, const float* __restrict__ bq,
    u16* __restrict__ Qs, u16* __restrict__ Ks, u16* __restrict__ Vs) {
  const int b = blockIdx.z, mt = blockIdx.y, n0 = blockIdx.x * 112;
  const int tid = threadIdx.x, lane = tid & 63, wave = tid >> 6;
  const int lm = lane & 15, lq = lane >> 4;
  __shared__ __align__(16) u16 Bl[112 * 40];
  f32x4 zf = {0.f, 0.f, 0.f, 0.f};
  f32x4 acc[7];
#pragma unroll
  for (int t = 0; t < 7; ++t) acc[t] = zf;
  const u16* Bb = xT + ((size_t)b * 784 + n0) * 512;
  const u16* Ar = W + (size_t)(mt * 64 + wave * 16 + lm) * 512;
  const int row0 = tid >> 2, seg8 = (tid & 3) * 8;
  const u16* src0 = Bb + (size_t)row0 * 512 + seg8;
  const u16* src1 = src0 + (size_t)64 * 512;
  u16* dst0 = &Bl[row0 * 40 + seg8];
  u16* dst1 = &Bl[(row0 + 64) * 40 + seg8];
  int4 p0 = *reinterpret_cast<const int4*>(src0);
  int4 p1;
  if (tid < 192) p1 = *reinterpret_cast<const int4*>(src1);
  bf16x8 afc = ld_bf8(Ar + lq * 8);
  for (int ks = 0; ks < 16; ++ks) {
    *reinterpret_cast<int4*>(dst0) = p0;
    if (tid < 192) *reinterpret_cast<int4*>(dst1) = p1;
    __syncthreads();
    bf16x8 af = afc;
    if (ks < 15) {
      p0 = *reinterpret_cast<const int4*>(src0 + (ks + 1) * 32);
      if (tid < 192) p1 = *reinterpret_cast<const int4*>(src1 + (ks + 1) * 32);
      afc = ld_bf8(Ar + (ks + 1) * 32 + lq * 8);
    }
#pragma unroll
    for (int t = 0; t < 7; ++t) {
      bf16x8 bf8 = ld_bf8(&Bl[(t * 16 + lm) * 40 + lq * 8]);
      acc[t] = MFMA16(af, bf8, acc[t]);
    }
    __syncthreads();
  }
  const int og = mt * 64 + wave * 16 + lq * 4;
  float sc[4], bi[4];
#pragma unroll
  for (int r = 0; r < 4; ++r) { sc[r] = gq[og + r] * INVS; bi[r] = bq[og + r]; }
  const int g = og >> 7, r128 = og & 127;
  const size_t bg = (size_t)b * 8 + g;
#pragma unroll
  for (int t = 0; t < 7; ++t) {
    int j = n0 + t * 16 + lm;
    u16 h[4];
#pragma unroll
    for (int r = 0; r < 4; ++r) h[r] = f2bf(acc[t][r] * sc[r] + bi[r]);
    if (r128 < 64) {
      u16* dst = (r128 < 32) ? Qs : Ks;
      int c = r128 & 31;
      u32 lo = (u32)h[0] | ((u32)h[1] << 16);
      u32 hi = (u32)h[2] | ((u32)h[3] << 16);
      *reinterpret_cast<int2*>(dst + (bg * 784 + j) * 32 + c) = make_int2((int)lo, (int)hi);
    } else {
      int c = r128 - 64;
#pragma unroll
      for (int r = 0; r < 4; ++r) Vs[(bg * 64 + c + r) * 784 + j] = h[r];
    }
  }
}

// ---------------- grouped 3x3 conv via 9 shifted MFMA passes ----------------
__global__ __launch_bounds__(256) void k_conv1(const u16* __restrict__ xT,
                                               const u16* __restrict__ W1t,
                                               u16* __restrict__ umid) {
  const int b = blockIdx.z, g = blockIdx.y, n0 = blockIdx.x * 112;
  const int tid = threadIdx.x, lane = tid & 63, wave = tid >> 6;
  const int lm = lane & 15, lq = lane >> 4;
  __shared__ __align__(16) u16 xl[170 * 72];
  for (int u = tid; u < 1360; u += 256) {
    int row = u >> 3, seg = u & 7;
    int ng = n0 - 29 + row;
    int4 v = {0, 0, 0, 0};
    if (ng >= 0 && ng < 784)
      v = *reinterpret_cast<const int4*>(xT + ((size_t)b * 784 + ng) * 512 + g * 64 + seg * 8);
    *reinterpret_cast<int4*>(&xl[row * 72 + seg * 8]) = v;
  }
  __syncthreads();
  f32x4 zf = {0.f, 0.f, 0.f, 0.f};
  f32x4 acc[7];
#pragma unroll
  for (int t = 0; t < 7; ++t) acc[t] = zf;
  const u16* Wg = W1t + (size_t)g * 9 * 4096;
#pragma unroll
  for (int k9 = 0; k9 < 9; ++k9) {
    const int dh = k9 / 3 - 1, dw = k9 % 3 - 1;
#pragma unroll
    for (int ks = 0; ks < 2; ++ks) {
      bf16x8 af = ld_bf8(Wg + (k9 * 64 + wave * 16 + lm) * 64 + ks * 32 + lq * 8);
#pragma unroll
      for (int t = 0; t < 7; ++t) {
        int n = n0 + t * 16 + lm;
        int ww = n % 28 + dw;
        bf16x8 bf8;
        if (ww >= 0 && ww < 28)
          bf8 = ld_bf8(&xl[(t * 16 + lm + dh * 28 + dw + 29) * 72 + ks * 32 + lq * 8]);
        else
          bf8 = zero8();
        acc[t] = MFMA16(af, bf8, acc[t]);
      }
    }
  }
  const int oc4 = g * 64 + wave * 16 + lq * 4;
#pragma unroll
  for (int t = 0; t < 7; ++t) {
    int j = n0 + t * 16 + lm;
    u16 h[4];
#pragma unroll
    for (int r = 0; r < 4; ++r) h[r] = f2bf(acc[t][r]);
    u32 lo = (u32)h[0] | ((u32)h[1] << 16);
    u32 hi = (u32)h[2] | ((u32)h[3] << 16);
    *reinterpret_cast<int2*>(umid + ((size_t)b * 784 + j) * 512 + oc4) = make_int2((int)lo, (int)hi);
  }
}

// ---------------- xw2 1x1 GEMM + bn -> unaryT32 (b,784,512) f32 ----------------
__global__ __launch_bounds__(256) void k_gemm_x2(
    const u16* __restrict__ W, const u16* __restrict__ Bsrc,
    const float* __restrict__ gv, const float* __restrict__ bv,
    float* __restrict__ outT) {
  const int b = blockIdx.z, mt = blockIdx.y, n0 = blockIdx.x * 112;
  const int tid = threadIdx.x, lane = tid & 63, wave = tid >> 6;
  const int lm = lane & 15, lq = lane >> 4;
  __shared__ __align__(16) u16 Bl[112 * 40];
  f32x4 zf = {0.f, 0.f, 0.f, 0.f};
  f32x4 acc[7];
#pragma unroll
  for (int t = 0; t < 7; ++t) acc[t] = zf;
  const u16* Bb = Bsrc + ((size_t)b * 784 + n0) * 512;
  const u16* Ar = W + (size_t)(mt * 64 + wave * 16 + lm) * 512;
  const int row0 = tid >> 2, seg8 = (tid & 3) * 8;
  const u16* src0 = Bb + (size_t)row0 * 512 + seg8;
  const u16* src1 = src0 + (size_t)64 * 512;
  u16* dst0 = &Bl[row0 * 40 + seg8];
  u16* dst1 = &Bl[(row0 + 64) * 40 + seg8];
  int4 p0 = *reinterpret_cast<const int4*>(src0);
  int4 p1;
  if (tid < 192) p1 = *reinterpret_cast<const int4*>(src1);
  bf16x8 afc = ld_bf8(Ar + lq * 8);
  for (int ks = 0; ks < 16; ++ks) {
    *reinterpret_cast<int4*>(dst0) = p0;
    if (tid < 192) *reinterpret_cast<int4*>(dst1) = p1;
    __syncthreads();
    bf16x8 af = afc;
    if (ks < 15) {
      p0 = *reinterpret_cast<const int4*>(src0 + (ks + 1) * 32);
      if (tid < 192) p1 = *reinterpret_cast<const int4*>(src1 + (ks + 1) * 32);
      afc = ld_bf8(Ar + (ks + 1) * 32 + lq * 8);
    }
#pragma unroll
    for (int t = 0; t < 7; ++t) {
      bf16x8 bf8 = ld_bf8(&Bl[(t * 16 + lm) * 40 + lq * 8]);
      acc[t] = MFMA16(af, bf8, acc[t]);
    }
    __syncthreads();
  }
  const int og = mt * 64 + wave * 16 + lq * 4;
  float sc[4], bi[4];
#pragma unroll
  for (int r = 0; r < 4; ++r) { sc[r] = gv[og + r] * INVS; bi[r] = bv[og + r]; }
#pragma unroll
  for (int t = 0; t < 7; ++t) {
    int j = n0 + t * 16 + lm;
    float4 o4;
    o4.x = acc[t][0] * sc[0] + bi[0];
    o4.y = acc[t][1] * sc[1] + bi[1];
    o4.z = acc[t][2] * sc[2] + bi[2];
    o4.w = acc[t][3] * sc[3] + bi[3];
    *reinterpret_cast<float4*>(outT + ((size_t)b * 784 + j) * 512 + og) = o4;
  }
}

// ---------------- fused attention per (b, g, 16-row i-tile) ----------------
// R5: logits packed fp16 pairs in registers Lp[13][2] (26 VGPRs). Pl holds ONLY
// bf16 P~ (written in phase 2 from registers). Header [0,16) + pads [784,872)
// zero for guard-free Psh gather. Row stride 872 u16.
__global__ __launch_bounds__(256) void k_attn(
    const u16* __restrict__ Qs, const u16* __restrict__ Ks, const u16* __restrict__ Vs,
    const u16* __restrict__ relq, const u16* __restrict__ relk, const u16* __restrict__ relv,
    const float* __restrict__ g_sim, const float* __restrict__ g_out,
    const float* __restrict__ b_out, float* __restrict__ binT) {
  const int b = blockIdx.z, g = blockIdx.y, i0 = blockIdx.x * 16;
  const int tid = threadIdx.x, lane = tid & 63, wave = tid >> 6;
  const int lm = lane & 15, lq = lane >> 4;
  __shared__ __align__(16) u16 Pl[16 + 16 * 872];
  __shared__ __align__(16) float KRs[4][16][34];  // per-wave KR band tile
  __shared__ float WM[4][16];                     // per-wave row max
  __shared__ float WS[4][16];                     // per-wave row sum
  // zero header [0,16) and right pads [784,872) of each row
  for (int u = tid; u < 1424; u += 256) {
    int idx = (u < 16) ? u : (16 + ((u - 16) / 88) * 872 + 784 + (u - 16) % 88);
    Pl[idx] = 0;
  }
  const float s0 = g_sim[g] * INVS, s1 = g_sim[8 + g] * INVS, s2 = g_sim[16 + g] * INVS;
  const size_t bg = (size_t)b * 8 + g;
  const u16* Qb = Qs + bg * 784 * 32;
  const u16* Kb = Ks + bg * 784 * 32;
  const u16* Vb = Vs + bg * 64 * 784;
  const bf16x8 aq = ld_bf8(Qb + (i0 + lm) * 32 + lq * 8);
  const f32x4 zf = {0.f, 0.f, 0.f, 0.f};
  // ---- phase 1: logits -> fp16-packed registers; wave owns j-tiles wave+4k ----
  u32 Lp[13][2];
  float vmax[4] = {-1e30f, -1e30f, -1e30f, -1e30f};
  bf16x8 kfc, bq0c, bq1c, bk0c, bk1c;
  {
    const int j0 = wave * 16;
    const int d0 = 768 + i0 - j0, e0 = 768 + j0 - i0;
    kfc = ld_bf8(Kb + (j0 + lm) * 32 + lq * 8);
    bq0c = ld_bf8(relq + (d0 + lm) * 32 + lq * 8);
    bq1c = ld_bf8(relq + (d0 + 16 + lm) * 32 + lq * 8);
    bk0c = ld_bf8(relk + (e0 + lm) * 32 + lq * 8);
    bk1c = ld_bf8(relk + (e0 + 16 + lm) * 32 + lq * 8);
  }
  int jt = wave;
#pragma unroll
  for (int rr = 0; rr < 13; ++rr) {
    const int jtn = jt + 4;
    bf16x8 kfn = kfc, bq0n = bq0c, bq1n = bq1c, bk0n = bk0c, bk1n = bk1c;
    if (jtn < 49) {
      const int j0n = jtn * 16;
      const int d0 = 768 + i0 - j0n, e0 = 768 + j0n - i0;
      kfn = ld_bf8(Kb + (j0n + lm) * 32 + lq * 8);
      bq0n = ld_bf8(relq + (d0 + lm) * 32 + lq * 8);
      bq1n = ld_bf8(relq + (d0 + 16 + lm) * 32 + lq * 8);
      bk0n = ld_bf8(relk + (e0 + lm) * 32 + lq * 8);
      bk1n = ld_bf8(relk + (e0 + 16 + lm) * 32 + lq * 8);
    }
    if (jt < 49) {
      f32x4 aqk = MFMA16(aq, kfc, zf);      // qk[i][j]
      f32x4 q0 = MFMA16(aq, bq0c, zf);      // QRt[i][d] cols 0..15
      f32x4 q1 = MFMA16(aq, bq1c, zf);      // cols 16..31
      f32x4 k0 = MFMA16(kfc, bk0c, zf);     // KRt[j][s] cols 0..15
      f32x4 k1 = MFMA16(kfc, bk1c, zf);
#pragma unroll
      for (int r = 0; r < 4; ++r) {
        int m = lq * 4 + r;
        KRs[wave][m][lm] = k0[r];
        KRs[wave][m][16 + lm] = k1[r];
      }
      float vals[4];
      // per-wave LDS RAW: compiler inserts lgkmcnt wait, no barrier needed
#pragma unroll
      for (int r = 0; r < 4; ++r) {
        int m = lq * 4 + r, n = lm;
        int c = m - n + 15;  // qr gather col
        int srcl = (c & 15) | (lane & 48);
        float t0 = bpermf(q0[r], srcl), t1 = bpermf(q1[r], srcl);
        float qv = (c & 16) ? t1 : t0;
        float kv = KRs[wave][n][n - m + 15];
        float val = aqk[r] * s0 + qv * s1 + kv * s2;  // b_sim drops (shift-invariant)
        vmax[r] = fmaxf(vmax[r], val);
        vals[r] = val;
      }
      Lp[rr][0] = packh2(vals[0], vals[1]);
      Lp[rr][1] = packh2(vals[2], vals[3]);
    }
    jt = jtn;
    kfc = kfn; bq0c = bq0n; bq1c = bq1n; bk0c = bk0n; bk1c = bk1n;
  }
  // wave-local row max reduce over n (lm bits)
#pragma unroll
  for (int r = 0; r < 4; ++r) {
#pragma unroll
    for (int d = 1; d < 16; d <<= 1) vmax[r] = fmaxf(vmax[r], __shfl_xor(vmax[r], d, 64));
  }
  if (lm == 0) {
#pragma unroll
    for (int r = 0; r < 4; ++r) WM[wave][lq * 4 + r] = vmax[r];
  }
  __syncthreads();
  // ---- phase 2: register softmax -> direct bf16 P~ writes ----
  float gmax[4], rsum[4] = {0.f, 0.f, 0.f, 0.f};
#pragma unroll
  for (int r = 0; r < 4; ++r) {
    int m = lq * 4 + r;
    gmax[r] = fmaxf(fmaxf(WM[0][m], WM[1][m]), fmaxf(WM[2][m], WM[3][m]));
  }
  int jt2 = wave;
#pragma unroll
  for (int rr = 0; rr < 13; ++rr) {
    if (jt2 < 49) {
#pragma unroll
      for (int h = 0; h < 2; ++h) {
        u32 pk = Lp[rr][h];
        int r0 = h * 2, r1 = h * 2 + 1;
        float e0 = __expf(unpklo(pk) - gmax[r0]);
        float e1 = __expf(unpkhi(pk) - gmax[r1]);
        rsum[r0] += e0;
        rsum[r1] += e1;
        Pl[16 + (lq * 4 + r0) * 872 + jt2 * 16 + lm] = f2bf(e0);
        Pl[16 + (lq * 4 + r1) * 872 + jt2 * 16 + lm] = f2bf(e1);
      }
    }
    jt2 += 4;
  }
#pragma unroll
  for (int r = 0; r < 4; ++r) {
#pragma unroll
    for (int d = 1; d < 16; d <<= 1) rsum[r] += __shfl_xor(rsum[r], d, 64);
  }
  if (lm == 0) {
#pragma unroll
    for (int r = 0; r < 4; ++r) WS[wave][lq * 4 + r] = rsum[r];
  }
  __syncthreads();
  // ---- phase 3: PV; wave = c-chunk of 16; sv = P~ @ V^T, sve = Psh @ relv^T ----
  f32x4 accV = zf, accE = zf;
  const int coff = wave * 16;
  const u16* Vr = Vb + (size_t)(coff + lm) * 784;
  const u16* Rr = relv + (size_t)(coff + lm) * 1600 + i0;
  const u16* Prow = &Pl[16 + lm * 872];
  for (int ks = 0; ks < 25; ++ks) {
    bf16x8 ap = ld_bf8(Prow + ks * 32 + lq * 8);  // cols>=784 read zero pad
    bf16x8 bv = ld_bf8(Vr + ks * 32 + lq * 8);
    accV = MFMA16(ap, bv, accV);
    const int base = 783 + lm - ks * 32 - lq * 8;  // Psh gather; pads/header give 0
    u16 h[8];
#pragma unroll
    for (int e = 0; e < 8; ++e) h[e] = Prow[base - e];
    bf16x8 ash = pack8(h);
    bf16x8 br = ld_bf8(Rr + ks * 32 + lq * 8);
    accE = MFMA16(ash, br, accE);
  }
  // ---- epilogue: binary[b, g*64+c, i] = bn(sv)+bn(sve), write (i, c) layout ----
  const int c = coff + lm;
  const int oi = g * 128 + 2 * c;
  const float so0 = g_out[oi] * INVS, bo0 = b_out[oi];
  const float so1 = g_out[oi + 1] * INVS, bo1 = b_out[oi + 1];
#pragma unroll
  for (int r = 0; r < 4; ++r) {
    int row = lq * 4 + r;
    float rl = 1.0f / (WS[0][row] + WS[1][row] + WS[2][row] + WS[3][row]);
    float val = accV[r] * rl * so0 + bo0 + accE[r] * rl * so1 + bo1;
    binT[((size_t)b * 784 + i0 + row) * 512 + g * 64 + c] = val;
  }
}

// ---------------- rw GEMM: relu(concat(unary,binary)) -> relu(bn) -> rT bf16 ----------------
__global__ __launch_bounds__(256) void k_gemm_rw(
    const u16* __restrict__ W, const float* __restrict__ unT, const float* __restrict__ binT,
    const float* __restrict__ gv, const float* __restrict__ bv, u16* __restrict__ rT) {
  const int b = blockIdx.z, mt = blockIdx.y, n0 = blockIdx.x * 112;
  const int tid = threadIdx.x, lane = tid & 63, wave = tid >> 6;
  const int lm = lane & 15, lq = lane >> 4;
  __shared__ __align__(16) u16 Bl[112 * 40];
  f32x4 zf = {0.f, 0.f, 0.f, 0.f};
  f32x4 acc[7];
#pragma unroll
  for (int t = 0; t < 7; ++t) acc[t] = zf;
  const u16* Ar = W + (size_t)(mt * 64 + wave * 16 + lm) * 1024;
  const int row0 = tid >> 2, seg8 = (tid & 3) * 8;
  const size_t off0 = ((size_t)b * 784 + n0 + row0) * 512 + seg8;
  const size_t off1 = off0 + (size_t)64 * 512;
  u16* dst0 = &Bl[row0 * 40 + seg8];
  u16* dst1 = &Bl[(row0 + 64) * 40 + seg8];
  auto ldrow = [](const float* sp, float4& a, float4& b) {
    a = *reinterpret_cast<const float4*>(sp);
    b = *reinterpret_cast<const float4*>(sp + 4);
  };
  auto cvt_store = [](u16* dst, float4 a, float4 b) {
    u16 h[8] = {f2bf(fmaxf(a.x, 0.f)), f2bf(fmaxf(a.y, 0.f)),
                f2bf(fmaxf(a.z, 0.f)), f2bf(fmaxf(a.w, 0.f)),
                f2bf(fmaxf(b.x, 0.f)), f2bf(fmaxf(b.y, 0.f)),
                f2bf(fmaxf(b.z, 0.f)), f2bf(fmaxf(b.w, 0.f))};
    *reinterpret_cast<int4*>(dst) = __builtin_bit_cast(int4, pack8(h));
  };
  float4 a0, b0, a1, b1;
  ldrow(unT + off0, a0, b0);
  if (tid < 192) ldrow(unT + off1, a1, b1);
  bf16x8 afc = ld_bf8(Ar + lq * 8);
  for (int ks = 0; ks < 32; ++ks) {
    cvt_store(dst0, a0, b0);
    if (tid < 192) cvt_store(dst1, a1, b1);
    __syncthreads();
    bf16x8 af = afc;
    if (ks < 31) {
      const int ksn = ks + 1;
      const float* sb = (ksn < 16) ? unT : binT;
      const int k0 = (ksn & 15) * 32;
      ldrow(sb + off0 + k0, a0, b0);
      if (tid < 192) ldrow(sb + off1 + k0, a1, b1);
      afc = ld_bf8(Ar + ksn * 32 + lq * 8);
    }
#pragma unroll
    for (int t = 0; t < 7; ++t) {
      bf16x8 bf8 = ld_bf8(&Bl[(t * 16 + lm) * 40 + lq * 8]);
      acc[t] = MFMA16(af, bf8, acc[t]);
    }
    __syncthreads();
  }
  const int og = mt * 64 + wave * 16 + lq * 4;
  float sc[4], bi[4];
#pragma unroll
  for (int r = 0; r < 4; ++r) { sc[r] = gv[og + r] * INVS; bi[r] = bv[og + r]; }
#pragma unroll
  for (int t = 0; t < 7; ++t) {
    int j = n0 + t * 16 + lm;
    u16 h[4];
#pragma unroll
    for (int r = 0; r < 4; ++r) h[r] = f2bf(fmaxf(acc[t][r] * sc[r] + bi[r], 0.f));
    u32 lo = (u32)h[0] | ((u32)h[1] << 16);
    u32 hi = (u32)h[2] | ((u32)h[3] << 16);
    *reinterpret_cast<int2*>(rT + ((size_t)b * 784 + j) * 512 + og) = make_int2((int)lo, (int)hi);
  }
}

// ---------------- pw GEMM + sigmoid gate + final fuse -> d_out ----------------
__global__ __launch_bounds__(256) void k_gemm_pw(
    const u16* __restrict__ W, const u16* __restrict__ rT,
    const float* __restrict__ gv, const float* __restrict__ bv,
    const float* __restrict__ binT, const float* __restrict__ unT,
    float* __restrict__ out) {
  const int b = blockIdx.z, mt = blockIdx.y, n0 = blockIdx.x * 112;
  const int tid = threadIdx.x, lane = tid & 63, wave = tid >> 6;
  const int lm = lane & 15, lq = lane >> 4;
  __shared__ __align__(16) u16 Bl[112 * 40];
  f32x4 zf = {0.f, 0.f, 0.f, 0.f};
  f32x4 acc[7];
#pragma unroll
  for (int t = 0; t < 7; ++t) acc[t] = zf;
  const u16* Bb = rT + ((size_t)b * 784 + n0) * 512;
  const u16* Ar = W + (size_t)(mt * 64 + wave * 16 + lm) * 512;
  const int row0 = tid >> 2, seg8 = (tid & 3) * 8;
  const u16* src0 = Bb + (size_t)row0 * 512 + seg8;
  const u16* src1 = src0 + (size_t)64 * 512;
  u16* dst0 = &Bl[row0 * 40 + seg8];
  u16* dst1 = &Bl[(row0 + 64) * 40 + seg8];
  int4 p0 = *reinterpret_cast<const int4*>(src0);
  int4 p1;
  if (tid < 192) p1 = *reinterpret_cast<const int4*>(src1);
  bf16x8 afc = ld_bf8(Ar + lq * 8);
  for (int ks = 0; ks < 16; ++ks) {
    *reinterpret_cast<int4*>(dst0) = p0;
    if (tid < 192) *reinterpret_cast<int4*>(dst1) = p1;
    __syncthreads();
    bf16x8 af = afc;
    if (ks < 15) {
      p0 = *reinterpret_cast<const int4*>(src0 + (ks + 1) * 32);
      if (tid < 192) p1 = *reinterpret_cast<const int4*>(src1 + (ks + 1) * 32);
      afc = ld_bf8(Ar + (ks + 1) * 32 + lq * 8);
    }
#pragma unroll
    for (int t = 0; t < 7; ++t) {
      bf16x8 bf8 = ld_bf8(&Bl[(t * 16 + lm) * 40 + lq * 8]);
      acc[t] = MFMA16(af, bf8, acc[t]);
    }
    __syncthreads();
  }
  const int og = mt * 64 + wave * 16 + lq * 4;
  float sc[4], bi[4];
#pragma unroll
  for (int r = 0; r < 4; ++r) { sc[r] = gv[og + r] * INVS; bi[r] = bv[og + r]; }
#pragma unroll
  for (int t = 0; t < 7; ++t) {
    int j = n0 + t * 16 + lm;
    float4 bin4 = *reinterpret_cast<const float4*>(binT + ((size_t)b * 784 + j) * 512 + og);
    float4 un4 = *reinterpret_cast<const float4*>(unT + ((size_t)b * 784 + j) * 512 + og);
    float binv[4] = {bin4.x, bin4.y, bin4.z, bin4.w};
    float unv[4] = {un4.x, un4.y, un4.z, un4.w};
#pragma unroll
    for (int r = 0; r < 4; ++r) {
      float gt = 1.f / (1.f + __expf(-(acc[t][r] * sc[r] + bi[r])));
      out[((size_t)b * 512 + og + r) * 784 + j] = gt * binv[r] + unv[r];
    }
  }
}

extern "C" void kernel_launch(void* const* d_in, const int* in_sizes, int n_in,
                              void* d_out, int out_size, void* d_ws, size_t ws_size,
                              hipStream_t stream) {
  const float* x = (const float*)d_in[0];
  const float* qkv_w = (const float*)d_in[1];
  const float* g_qkv = (const float*)d_in[2];
  const float* b_qkv = (const float*)d_in[3];
  const float* g_sim = (const float*)d_in[4];
  // d_in[5] = b_sim: unused (softmax is shift-invariant per (b,g) row)
  const float* g_out = (const float*)d_in[6];
  const float* b_out = (const float*)d_in[7];
  const float* relative = (const float*)d_in[8];
  const float* xw1 = (const float*)d_in[9];
  const float* xw2 = (const float*)d_in[10];
  const float* g_x = (const float*)d_in[11];
  const float* b_x = (const float*)d_in[12];
  const float* rw = (const float*)d_in[13];
  const float* g_r = (const float*)d_in[14];
  const float* b_r = (const float*)d_in[15];
  const float* pw = (const float*)d_in[16];
  const float* g_p = (const float*)d_in[17];
  const float* b_p = (const float*)d_in[18];

  char* p = (char*)d_ws;
  auto take = [&](size_t n) { char* q = p; p += (n + 255) & ~(size_t)255; return q; };
  u16* xT = (u16*)take((size_t)8 * 784 * 512 * 2);
  u16* Wq = (u16*)take((size_t)1024 * 512 * 2);
  u16* W2 = (u16*)take((size_t)512 * 512 * 2);
  u16* Wr = (u16*)take((size_t)512 * 1024 * 2);
  u16* Wp = (u16*)take((size_t)512 * 512 * 2);
  u16* W1t = (u16*)take((size_t)294912 * 2);
  u16* relq = (u16*)take((size_t)51200 * 2);
  u16* relk = (u16*)take((size_t)51200 * 2);
  u16* relv = (u16*)take((size_t)102400 * 2);
  u16* Qs = (u16*)take((size_t)8 * 8 * 784 * 32 * 2);
  u16* Ks = (u16*)take((size_t)8 * 8 * 784 * 32 * 2);
  u16* Vs = (u16*)take(((size_t)8 * 8 * 64 * 784 + 64) * 2);  // +64 pad for K=800 reads
  u16* umid = (u16*)take((size_t)8 * 784 * 512 * 2);
  float* unT = (float*)take((size_t)8 * 784 * 512 * 4);
  float* binT = (float*)take((size_t)8 * 784 * 512 * 4);
  u16* rT = (u16*)take((size_t)8 * 784 * 512 * 2);

  k_prep<<<dim3(8096), dim3(256), 0, stream>>>(qkv_w, xw2, rw, pw, xw1, relative,
                                               Wq, W2, Wr, Wp, W1t, relq, relk, relv);
  k_transpose<<<dim3(25, 8, 8), dim3(256), 0, stream>>>(x, xT);
  k_gemm_qkv<<<dim3(7, 16, 8), dim3(256), 0, stream>>>(Wq, xT, g_qkv, b_qkv, Qs, Ks, Vs);
  k_conv1<<<dim3(7, 8, 8), dim3(256), 0, stream>>>(xT, W1t, umid);
  k_gemm_x2<<<dim3(7, 8, 8), dim3(256), 0, stream>>>(W2, umid, g_x, b_x, unT);
  k_attn<<<dim3(49, 8, 8), dim3(256), 0, stream>>>(Qs, Ks, Vs, relq, relk, relv,
                                                   g_sim, g_out, b_out, binT);
  k_gemm_rw<<<dim3(7, 8, 8), dim3(256), 0, stream>>>(Wr, unT, binT, g_r, b_r, rT);
  k_gemm_pw<<<dim3(7, 8, 8), dim3(256), 0, stream>>>(Wp, rT, g_p, b_p, binT, unT,
                                                     (float*)d_out);
}

// Round 6
// 300.963 us; speedup vs baseline: 1.1741x; 1.1741x over previous
//
#include <hip/hip_runtime.h>
#include <math.h>

// LESA block for MI355X. N=8, C=512, H=W=28 (HW=784), G=8, QKP=32, VP=64, BP=512.
// R6: recombination — k_attn from R4 (fp16 logits in LDS, VGPR 60, 4 blk/CU)
// + GEMMs from R5 (1-deep register prefetch of staging quanta + A-frag).

typedef unsigned short u16;
typedef unsigned int u32;
typedef __bf16 bf16x8 __attribute__((ext_vector_type(8)));
typedef float f32x4 __attribute__((ext_vector_type(4)));

#define INVS 0.99999500003749968f  // 1/sqrt(1+1e-5)
#define MFMA16(a, b, c) __builtin_amdgcn_mfma_f32_16x16x32_bf16(a, b, c, 0, 0, 0)

__device__ inline u16 f2bf(float f) {
  u32 u = __builtin_bit_cast(u32, f);
  return (u16)((u + 0x7fffu + ((u >> 16) & 1u)) >> 16);
}
__device__ inline bf16x8 ld_bf8(const u16* p) {
  int4 v = *reinterpret_cast<const int4*>(p);
  return __builtin_bit_cast(bf16x8, v);
}
__device__ inline bf16x8 pack8(const u16 h[8]) {
  int4 v;
  v.x = (int)((u32)h[0] | ((u32)h[1] << 16));
  v.y = (int)((u32)h[2] | ((u32)h[3] << 16));
  v.z = (int)((u32)h[4] | ((u32)h[5] << 16));
  v.w = (int)((u32)h[6] | ((u32)h[7] << 16));
  return __builtin_bit_cast(bf16x8, v);
}
__device__ inline bf16x8 zero8() {
  int4 z = {0, 0, 0, 0};
  return __builtin_bit_cast(bf16x8, z);
}
__device__ inline float bpermf(float v, int srcl) {
  return __builtin_bit_cast(float,
      __builtin_amdgcn_ds_bpermute(srcl << 2, __builtin_bit_cast(int, v)));
}

// ---------------- prep: weight casts/permutes + relative tables ----------------
__global__ __launch_bounds__(256) void k_prep(
    const float* __restrict__ qkv_w, const float* __restrict__ xw2,
    const float* __restrict__ rw, const float* __restrict__ pw,
    const float* __restrict__ xw1, const float* __restrict__ rel,
    u16* __restrict__ Wq, u16* __restrict__ W2, u16* __restrict__ Wr,
    u16* __restrict__ Wp, u16* __restrict__ W1t, u16* __restrict__ relq,
    u16* __restrict__ relk, u16* __restrict__ relv) {
  int idx = blockIdx.x * 256 + threadIdx.x;
  if (idx < 524288) { Wq[idx] = f2bf(qkv_w[idx]); return; }
  idx -= 524288;
  if (idx < 262144) { W2[idx] = f2bf(xw2[idx]); return; }
  idx -= 262144;
  if (idx < 524288) { Wr[idx] = f2bf(rw[idx]); return; }
  idx -= 524288;
  if (idx < 262144) { Wp[idx] = f2bf(pw[idx]); return; }
  idx -= 262144;
  if (idx < 294912) {  // W1t[(g*9+k9)*64 + oc][ic] = xw1[g*64+oc][ic][kh][kw]
    int gk = idx >> 12, rem = idx & 4095, oc = rem >> 6, ic = rem & 63;
    int g = gk / 9, k9 = gk % 9;
    W1t[idx] = f2bf(xw1[(((g * 64 + oc) * 64) + ic) * 9 + k9]);
    return;
  }
  idx -= 294912;
  if (idx < 51200) {  // relq[t][c] = relative[c][t], t<1600 (pad 0)
    int t = idx >> 5, c = idx & 31;
    relq[idx] = (t < 1567) ? f2bf(rel[c * 1567 + t]) : (u16)0;
    return;
  }
  idx -= 51200;
  if (idx < 51200) {
    int t = idx >> 5, c = idx & 31;
    relk[idx] = (t < 1567) ? f2bf(rel[(32 + c) * 1567 + t]) : (u16)0;
    return;
  }
  idx -= 51200;
  if (idx < 102400) {  // relv[c][t] (c<64, t<1600 pad 0)
    int c = idx / 1600, t = idx % 1600;
    relv[idx] = (t < 1567) ? f2bf(rel[(64 + c) * 1567 + t]) : (u16)0;
    return;
  }
}

// ---------------- transpose x (b,512,784) f32 -> xT (b,784,512) bf16 ----------------
__global__ __launch_bounds__(256) void k_transpose(const float* __restrict__ x,
                                                   u16* __restrict__ xT) {
  const int b = blockIdx.z, c0 = blockIdx.y * 64, n0 = blockIdx.x * 32;
  const int tid = threadIdx.x;
  __shared__ __align__(16) u16 tl[64][36];
#pragma unroll
  for (int h = 0; h < 2; ++h) {
    int cl = (tid >> 3) + h * 32;
    int n4 = (tid & 7) * 4;
    float4 v = {0.f, 0.f, 0.f, 0.f};
    if (n0 + n4 + 3 < 784)
      v = *reinterpret_cast<const float4*>(x + ((size_t)b * 512 + c0 + cl) * 784 + n0 + n4);
    u32 lo = (u32)f2bf(v.x) | ((u32)f2bf(v.y) << 16);
    u32 hi = (u32)f2bf(v.z) | ((u32)f2bf(v.w) << 16);
    *reinterpret_cast<int2*>(&tl[cl][n4]) = make_int2((int)lo, (int)hi);
  }
  __syncthreads();
  int nl = tid >> 3, c8 = (tid & 7) * 8;
  if (n0 + nl < 784) {
    u16 h[8];
#pragma unroll
    for (int e = 0; e < 8; ++e) h[e] = tl[c8 + e][nl];
    *reinterpret_cast<int4*>(xT + ((size_t)b * 784 + n0 + nl) * 512 + c0 + c8) =
        __builtin_bit_cast(int4, pack8(h));
  }
}

// ---------------- qkv GEMM: (1024x512)@(512x784) + bn -> Q,K (j,c) / V (c,j) bf16 ----------------
__global__ __launch_bounds__(256) void k_gemm_qkv(
    const u16* __restrict__ W, const u16* __restrict__ xT,
    const float* __restrict__ gq, const float* __restrict__ bq,
    u16* __restrict__ Qs, u16* __restrict__ Ks, u16* __restrict__ Vs) {
  const int b = blockIdx.z, mt = blockIdx.y, n0 = blockIdx.x * 112;
  const int tid = threadIdx.x, lane = tid & 63, wave = tid >> 6;
  const int lm = lane & 15, lq = lane >> 4;
  __shared__ __align__(16) u16 Bl[112 * 40];
  f32x4 zf = {0.f, 0.f, 0.f, 0.f};
  f32x4 acc[7];
#pragma unroll
  for (int t = 0; t < 7; ++t) acc[t] = zf;
  const u16* Bb = xT + ((size_t)b * 784 + n0) * 512;
  const u16* Ar = W + (size_t)(mt * 64 + wave * 16 + lm) * 512;
  const int row0 = tid >> 2, seg8 = (tid & 3) * 8;
  const u16* src0 = Bb + (size_t)row0 * 512 + seg8;
  const u16* src1 = src0 + (size_t)64 * 512;
  u16* dst0 = &Bl[row0 * 40 + seg8];
  u16* dst1 = &Bl[(row0 + 64) * 40 + seg8];
  int4 p0 = *reinterpret_cast<const int4*>(src0);
  int4 p1;
  if (tid < 192) p1 = *reinterpret_cast<const int4*>(src1);
  bf16x8 afc = ld_bf8(Ar + lq * 8);
  for (int ks = 0; ks < 16; ++ks) {
    *reinterpret_cast<int4*>(dst0) = p0;
    if (tid < 192) *reinterpret_cast<int4*>(dst1) = p1;
    __syncthreads();
    bf16x8 af = afc;
    if (ks < 15) {
      p0 = *reinterpret_cast<const int4*>(src0 + (ks + 1) * 32);
      if (tid < 192) p1 = *reinterpret_cast<const int4*>(src1 + (ks + 1) * 32);
      afc = ld_bf8(Ar + (ks + 1) * 32 + lq * 8);
    }
#pragma unroll
    for (int t = 0; t < 7; ++t) {
      bf16x8 bf8 = ld_bf8(&Bl[(t * 16 + lm) * 40 + lq * 8]);
      acc[t] = MFMA16(af, bf8, acc[t]);
    }
    __syncthreads();
  }
  const int og = mt * 64 + wave * 16 + lq * 4;
  float sc[4], bi[4];
#pragma unroll
  for (int r = 0; r < 4; ++r) { sc[r] = gq[og + r] * INVS; bi[r] = bq[og + r]; }
  const int g = og >> 7, r128 = og & 127;
  const size_t bg = (size_t)b * 8 + g;
#pragma unroll
  for (int t = 0; t < 7; ++t) {
    int j = n0 + t * 16 + lm;
    u16 h[4];
#pragma unroll
    for (int r = 0; r < 4; ++r) h[r] = f2bf(acc[t][r] * sc[r] + bi[r]);
    if (r128 < 64) {
      u16* dst = (r128 < 32) ? Qs : Ks;
      int c = r128 & 31;
      u32 lo = (u32)h[0] | ((u32)h[1] << 16);
      u32 hi = (u32)h[2] | ((u32)h[3] << 16);
      *reinterpret_cast<int2*>(dst + (bg * 784 + j) * 32 + c) = make_int2((int)lo, (int)hi);
    } else {
      int c = r128 - 64;
#pragma unroll
      for (int r = 0; r < 4; ++r) Vs[(bg * 64 + c + r) * 784 + j] = h[r];
    }
  }
}

// ---------------- grouped 3x3 conv via 9 shifted MFMA passes ----------------
__global__ __launch_bounds__(256) void k_conv1(const u16* __restrict__ xT,
                                               const u16* __restrict__ W1t,
                                               u16* __restrict__ umid) {
  const int b = blockIdx.z, g = blockIdx.y, n0 = blockIdx.x * 112;
  const int tid = threadIdx.x, lane = tid & 63, wave = tid >> 6;
  const int lm = lane & 15, lq = lane >> 4;
  __shared__ __align__(16) u16 xl[170 * 72];
  for (int u = tid; u < 1360; u += 256) {
    int row = u >> 3, seg = u & 7;
    int ng = n0 - 29 + row;
    int4 v = {0, 0, 0, 0};
    if (ng >= 0 && ng < 784)
      v = *reinterpret_cast<const int4*>(xT + ((size_t)b * 784 + ng) * 512 + g * 64 + seg * 8);
    *reinterpret_cast<int4*>(&xl[row * 72 + seg * 8]) = v;
  }
  __syncthreads();
  f32x4 zf = {0.f, 0.f, 0.f, 0.f};
  f32x4 acc[7];
#pragma unroll
  for (int t = 0; t < 7; ++t) acc[t] = zf;
  const u16* Wg = W1t + (size_t)g * 9 * 4096;
#pragma unroll
  for (int k9 = 0; k9 < 9; ++k9) {
    const int dh = k9 / 3 - 1, dw = k9 % 3 - 1;
#pragma unroll
    for (int ks = 0; ks < 2; ++ks) {
      bf16x8 af = ld_bf8(Wg + (k9 * 64 + wave * 16 + lm) * 64 + ks * 32 + lq * 8);
#pragma unroll
      for (int t = 0; t < 7; ++t) {
        int n = n0 + t * 16 + lm;
        int ww = n % 28 + dw;
        bf16x8 bf8;
        if (ww >= 0 && ww < 28)
          bf8 = ld_bf8(&xl[(t * 16 + lm + dh * 28 + dw + 29) * 72 + ks * 32 + lq * 8]);
        else
          bf8 = zero8();
        acc[t] = MFMA16(af, bf8, acc[t]);
      }
    }
  }
  const int oc4 = g * 64 + wave * 16 + lq * 4;
#pragma unroll
  for (int t = 0; t < 7; ++t) {
    int j = n0 + t * 16 + lm;
    u16 h[4];
#pragma unroll
    for (int r = 0; r < 4; ++r) h[r] = f2bf(acc[t][r]);
    u32 lo = (u32)h[0] | ((u32)h[1] << 16);
    u32 hi = (u32)h[2] | ((u32)h[3] << 16);
    *reinterpret_cast<int2*>(umid + ((size_t)b * 784 + j) * 512 + oc4) = make_int2((int)lo, (int)hi);
  }
}

// ---------------- xw2 1x1 GEMM + bn -> unaryT32 (b,784,512) f32 ----------------
__global__ __launch_bounds__(256) void k_gemm_x2(
    const u16* __restrict__ W, const u16* __restrict__ Bsrc,
    const float* __restrict__ gv, const float* __restrict__ bv,
    float* __restrict__ outT) {
  const int b = blockIdx.z, mt = blockIdx.y, n0 = blockIdx.x * 112;
  const int tid = threadIdx.x, lane = tid & 63, wave = tid >> 6;
  const int lm = lane & 15, lq = lane >> 4;
  __shared__ __align__(16) u16 Bl[112 * 40];
  f32x4 zf = {0.f, 0.f, 0.f, 0.f};
  f32x4 acc[7];
#pragma unroll
  for (int t = 0; t < 7; ++t) acc[t] = zf;
  const u16* Bb = Bsrc + ((size_t)b * 784 + n0) * 512;
  const u16* Ar = W + (size_t)(mt * 64 + wave * 16 + lm) * 512;
  const int row0 = tid >> 2, seg8 = (tid & 3) * 8;
  const u16* src0 = Bb + (size_t)row0 * 512 + seg8;
  const u16* src1 = src0 + (size_t)64 * 512;
  u16* dst0 = &Bl[row0 * 40 + seg8];
  u16* dst1 = &Bl[(row0 + 64) * 40 + seg8];
  int4 p0 = *reinterpret_cast<const int4*>(src0);
  int4 p1;
  if (tid < 192) p1 = *reinterpret_cast<const int4*>(src1);
  bf16x8 afc = ld_bf8(Ar + lq * 8);
  for (int ks = 0; ks < 16; ++ks) {
    *reinterpret_cast<int4*>(dst0) = p0;
    if (tid < 192) *reinterpret_cast<int4*>(dst1) = p1;
    __syncthreads();
    bf16x8 af = afc;
    if (ks < 15) {
      p0 = *reinterpret_cast<const int4*>(src0 + (ks + 1) * 32);
      if (tid < 192) p1 = *reinterpret_cast<const int4*>(src1 + (ks + 1) * 32);
      afc = ld_bf8(Ar + (ks + 1) * 32 + lq * 8);
    }
#pragma unroll
    for (int t = 0; t < 7; ++t) {
      bf16x8 bf8 = ld_bf8(&Bl[(t * 16 + lm) * 40 + lq * 8]);
      acc[t] = MFMA16(af, bf8, acc[t]);
    }
    __syncthreads();
  }
  const int og = mt * 64 + wave * 16 + lq * 4;
  float sc[4], bi[4];
#pragma unroll
  for (int r = 0; r < 4; ++r) { sc[r] = gv[og + r] * INVS; bi[r] = bv[og + r]; }
#pragma unroll
  for (int t = 0; t < 7; ++t) {
    int j = n0 + t * 16 + lm;
    float4 o4;
    o4.x = acc[t][0] * sc[0] + bi[0];
    o4.y = acc[t][1] * sc[1] + bi[1];
    o4.z = acc[t][2] * sc[2] + bi[2];
    o4.w = acc[t][3] * sc[3] + bi[3];
    *reinterpret_cast<float4*>(outT + ((size_t)b * 784 + j) * 512 + og) = o4;
  }
}

// ---------------- fused attention per (b, g, 16-row i-tile) ----------------
// R4 LDS layout: Pl u16[16 + 16*872]; row m base = 16+m*872; cols [0,784) hold
// fp16 logits (phase 1-2), then bf16 P~ in-place (same addr, read-before-write,
// wave-lockstep-safe). Header [0,16) + right pads [784,872) are zero for
// guard-free Psh gather (negative reach lands in prev row's zero pad).
__global__ __launch_bounds__(256) void k_attn(
    const u16* __restrict__ Qs, const u16* __restrict__ Ks, const u16* __restrict__ Vs,
    const u16* __restrict__ relq, const u16* __restrict__ relk, const u16* __restrict__ relv,
    const float* __restrict__ g_sim, const float* __restrict__ g_out,
    const float* __restrict__ b_out, float* __restrict__ binT) {
  const int b = blockIdx.z, g = blockIdx.y, i0 = blockIdx.x * 16;
  const int tid = threadIdx.x, lane = tid & 63, wave = tid >> 6;
  const int lm = lane & 15, lq = lane >> 4;
  __shared__ __align__(16) u16 Pl[16 + 16 * 872];
  __shared__ __align__(16) float KRs[4][16][34];  // per-wave KR band tile
  __shared__ float WM[4][16];                     // per-wave row max
  __shared__ float rstat[16];
  // zero header [0,16) and right pads [784,872) of each row
  for (int u = tid; u < 1424; u += 256) {
    int idx = (u < 16) ? u : (16 + ((u - 16) / 88) * 872 + 784 + (u - 16) % 88);
    Pl[idx] = 0;
  }
  const float s0 = g_sim[g] * INVS, s1 = g_sim[8 + g] * INVS, s2 = g_sim[16 + g] * INVS;
  const size_t bg = (size_t)b * 8 + g;
  const u16* Qb = Qs + bg * 784 * 32;
  const u16* Kb = Ks + bg * 784 * 32;
  const u16* Vb = Vs + bg * 64 * 784;
  const bf16x8 aq = ld_bf8(Qb + (i0 + lm) * 32 + lq * 8);
  const f32x4 zf = {0.f, 0.f, 0.f, 0.f};
  // ---- phase 1: logits -> fp16 LDS; wave owns j-tiles wave, wave+4, ... ----
  float vmax[4] = {-1e30f, -1e30f, -1e30f, -1e30f};
  bf16x8 kfc, bq0c, bq1c, bk0c, bk1c;
  {
    const int j0 = wave * 16;
    const int d0 = 768 + i0 - j0, e0 = 768 + j0 - i0;
    kfc = ld_bf8(Kb + (j0 + lm) * 32 + lq * 8);
    bq0c = ld_bf8(relq + (d0 + lm) * 32 + lq * 8);
    bq1c = ld_bf8(relq + (d0 + 16 + lm) * 32 + lq * 8);
    bk0c = ld_bf8(relk + (e0 + lm) * 32 + lq * 8);
    bk1c = ld_bf8(relk + (e0 + 16 + lm) * 32 + lq * 8);
  }
  int jt = wave;
  for (int rr = 0; rr < 13; ++rr) {
    const int jtn = jt + 4;
    bf16x8 kfn = kfc, bq0n = bq0c, bq1n = bq1c, bk0n = bk0c, bk1n = bk1c;
    if (jtn < 49) {
      const int j0n = jtn * 16;
      const int d0 = 768 + i0 - j0n, e0 = 768 + j0n - i0;
      kfn = ld_bf8(Kb + (j0n + lm) * 32 + lq * 8);
      bq0n = ld_bf8(relq + (d0 + lm) * 32 + lq * 8);
      bq1n = ld_bf8(relq + (d0 + 16 + lm) * 32 + lq * 8);
      bk0n = ld_bf8(relk + (e0 + lm) * 32 + lq * 8);
      bk1n = ld_bf8(relk + (e0 + 16 + lm) * 32 + lq * 8);
    }
    if (jt < 49) {
      const int j0 = jt * 16;
      f32x4 aqk = MFMA16(aq, kfc, zf);      // qk[i][j]
      f32x4 q0 = MFMA16(aq, bq0c, zf);      // QRt[i][d] cols 0..15
      f32x4 q1 = MFMA16(aq, bq1c, zf);      // cols 16..31
      f32x4 k0 = MFMA16(kfc, bk0c, zf);     // KRt[j][s] cols 0..15
      f32x4 k1 = MFMA16(kfc, bk1c, zf);
#pragma unroll
      for (int r = 0; r < 4; ++r) {
        int m = lq * 4 + r;
        KRs[wave][m][lm] = k0[r];
        KRs[wave][m][16 + lm] = k1[r];
      }
      // per-wave LDS RAW: compiler inserts lgkmcnt wait, no barrier needed
#pragma unroll
      for (int r = 0; r < 4; ++r) {
        int m = lq * 4 + r, n = lm;
        int c = m - n + 15;  // qr gather col
        int srcl = (c & 15) | (lane & 48);
        float t0 = bpermf(q0[r], srcl), t1 = bpermf(q1[r], srcl);
        float qv = (c & 16) ? t1 : t0;
        float kv = KRs[wave][n][n - m + 15];
        float val = aqk[r] * s0 + qv * s1 + kv * s2;  // b_sim drops (shift-invariant)
        vmax[r] = fmaxf(vmax[r], val);
        _Float16 hv = (_Float16)val;
        Pl[16 + m * 872 + j0 + n] = __builtin_bit_cast(u16, hv);
      }
    }
    jt = jtn;
    kfc = kfn; bq0c = bq0n; bq1c = bq1n; bk0c = bk0n; bk1c = bk1n;
  }
  // wave-local row max reduce over n (lm bits)
#pragma unroll
  for (int r = 0; r < 4; ++r) {
#pragma unroll
    for (int d = 1; d < 16; d <<= 1) vmax[r] = fmaxf(vmax[r], __shfl_xor(vmax[r], d, 64));
  }
  if (lm == 0) {
#pragma unroll
    for (int r = 0; r < 4; ++r) WM[wave][lq * 4 + r] = vmax[r];
  }
  __syncthreads();
  // ---- phase 2: softmax, fp16 -> bf16 P~ IN-PLACE (same index, same size) ----
  {
    const int row = tid >> 4, sub = tid & 15;
    u16* Pr = &Pl[16 + row * 872];
    float gmax = fmaxf(fmaxf(WM[0][row], WM[1][row]), fmaxf(WM[2][row], WM[3][row]));
    float sm = 0.f;
    for (int k = 0; k < 49; ++k) {
      int j = sub + 16 * k;
      _Float16 hv = __builtin_bit_cast(_Float16, Pr[j]);
      float e = __expf((float)hv - gmax);
      sm += e;
      Pr[j] = f2bf(e);
    }
#pragma unroll
    for (int d = 1; d < 16; d <<= 1) sm += __shfl_xor(sm, d, 64);
    if (sub == 0) rstat[row] = 1.0f / sm;
  }
  __syncthreads();
  // ---- phase 3: PV; wave = c-chunk of 16; sv = P~ @ V^T, sve = Psh @ relv^T ----
  f32x4 accV = zf, accE = zf;
  const int coff = wave * 16;
  const u16* Vr = Vb + (size_t)(coff + lm) * 784;
  const u16* Rr = relv + (size_t)(coff + lm) * 1600 + i0;
  const u16* Prow = &Pl[16 + lm * 872];
  for (int ks = 0; ks < 25; ++ks) {
    bf16x8 ap = ld_bf8(Prow + ks * 32 + lq * 8);  // cols>=784 read zero pad
    bf16x8 bv = ld_bf8(Vr + ks * 32 + lq * 8);
    accV = MFMA16(ap, bv, accV);
    const int base = 783 + lm - ks * 32 - lq * 8;  // Psh gather; pads/header give 0
    u16 h[8];
#pragma unroll
    for (int e = 0; e < 8; ++e) h[e] = Prow[base - e];
    bf16x8 ash = pack8(h);
    bf16x8 br = ld_bf8(Rr + ks * 32 + lq * 8);
    accE = MFMA16(ash, br, accE);
  }
  // ---- epilogue: binary[b, g*64+c, i] = bn(sv)+bn(sve), write (i, c) layout ----
  const int c = coff + lm;
  const int oi = g * 128 + 2 * c;
  const float so0 = g_out[oi] * INVS, bo0 = b_out[oi];
  const float so1 = g_out[oi + 1] * INVS, bo1 = b_out[oi + 1];
#pragma unroll
  for (int r = 0; r < 4; ++r) {
    int row = lq * 4 + r;
    float rl = rstat[row];
    float val = accV[r] * rl * so0 + bo0 + accE[r] * rl * so1 + bo1;
    binT[((size_t)b * 784 + i0 + row) * 512 + g * 64 + c] = val;
  }
}

// ---------------- rw GEMM: relu(concat(unary,binary)) -> relu(bn) -> rT bf16 ----------------
__global__ __launch_bounds__(256) void k_gemm_rw(
    const u16* __restrict__ W, const float* __restrict__ unT, const float* __restrict__ binT,
    const float* __restrict__ gv, const float* __restrict__ bv, u16* __restrict__ rT) {
  const int b = blockIdx.z, mt = blockIdx.y, n0 = blockIdx.x * 112;
  const int tid = threadIdx.x, lane = tid & 63, wave = tid >> 6;
  const int lm = lane & 15, lq = lane >> 4;
  __shared__ __align__(16) u16 Bl[112 * 40];
  f32x4 zf = {0.f, 0.f, 0.f, 0.f};
  f32x4 acc[7];
#pragma unroll
  for (int t = 0; t < 7; ++t) acc[t] = zf;
  const u16* Ar = W + (size_t)(mt * 64 + wave * 16 + lm) * 1024;
  const int row0 = tid >> 2, seg8 = (tid & 3) * 8;
  const size_t off0 = ((size_t)b * 784 + n0 + row0) * 512 + seg8;
  const size_t off1 = off0 + (size_t)64 * 512;
  u16* dst0 = &Bl[row0 * 40 + seg8];
  u16* dst1 = &Bl[(row0 + 64) * 40 + seg8];
  auto ldrow = [](const float* sp, float4& a, float4& b) {
    a = *reinterpret_cast<const float4*>(sp);
    b = *reinterpret_cast<const float4*>(sp + 4);
  };
  auto cvt_store = [](u16* dst, float4 a, float4 b) {
    u16 h[8] = {f2bf(fmaxf(a.x, 0.f)), f2bf(fmaxf(a.y, 0.f)),
                f2bf(fmaxf(a.z, 0.f)), f2bf(fmaxf(a.w, 0.f)),
                f2bf(fmaxf(b.x, 0.f)), f2bf(fmaxf(b.y, 0.f)),
                f2bf(fmaxf(b.z, 0.f)), f2bf(fmaxf(b.w, 0.f))};
    *reinterpret_cast<int4*>(dst) = __builtin_bit_cast(int4, pack8(h));
  };
  float4 a0, b0, a1, b1;
  ldrow(unT + off0, a0, b0);
  if (tid < 192) ldrow(unT + off1, a1, b1);
  bf16x8 afc = ld_bf8(Ar + lq * 8);
  for (int ks = 0; ks < 32; ++ks) {
    cvt_store(dst0, a0, b0);
    if (tid < 192) cvt_store(dst1, a1, b1);
    __syncthreads();
    bf16x8 af = afc;
    if (ks < 31) {
      const int ksn = ks + 1;
      const float* sb = (ksn < 16) ? unT : binT;
      const int k0 = (ksn & 15) * 32;
      ldrow(sb + off0 + k0, a0, b0);
      if (tid < 192) ldrow(sb + off1 + k0, a1, b1);
      afc = ld_bf8(Ar + ksn * 32 + lq * 8);
    }
#pragma unroll
    for (int t = 0; t < 7; ++t) {
      bf16x8 bf8 = ld_bf8(&Bl[(t * 16 + lm) * 40 + lq * 8]);
      acc[t] = MFMA16(af, bf8, acc[t]);
    }
    __syncthreads();
  }
  const int og = mt * 64 + wave * 16 + lq * 4;
  float sc[4], bi[4];
#pragma unroll
  for (int r = 0; r < 4; ++r) { sc[r] = gv[og + r] * INVS; bi[r] = bv[og + r]; }
#pragma unroll
  for (int t = 0; t < 7; ++t) {
    int j = n0 + t * 16 + lm;
    u16 h[4];
#pragma unroll
    for (int r = 0; r < 4; ++r) h[r] = f2bf(fmaxf(acc[t][r] * sc[r] + bi[r], 0.f));
    u32 lo = (u32)h[0] | ((u32)h[1] << 16);
    u32 hi = (u32)h[2] | ((u32)h[3] << 16);
    *reinterpret_cast<int2*>(rT + ((size_t)b * 784 + j) * 512 + og) = make_int2((int)lo, (int)hi);
  }
}

// ---------------- pw GEMM + sigmoid gate + final fuse -> d_out ----------------
__global__ __launch_bounds__(256) void k_gemm_pw(
    const u16* __restrict__ W, const u16* __restrict__ rT,
    const float* __restrict__ gv, const float* __restrict__ bv,
    const float* __restrict__ binT, const float* __restrict__ unT,
    float* __restrict__ out) {
  const int b = blockIdx.z, mt = blockIdx.y, n0 = blockIdx.x * 112;
  const int tid = threadIdx.x, lane = tid & 63, wave = tid >> 6;
  const int lm = lane & 15, lq = lane >> 4;
  __shared__ __align__(16) u16 Bl[112 * 40];
  f32x4 zf = {0.f, 0.f, 0.f, 0.f};
  f32x4 acc[7];
#pragma unroll
  for (int t = 0; t < 7; ++t) acc[t] = zf;
  const u16* Bb = rT + ((size_t)b * 784 + n0) * 512;
  const u16* Ar = W + (size_t)(mt * 64 + wave * 16 + lm) * 512;
  const int row0 = tid >> 2, seg8 = (tid & 3) * 8;
  const u16* src0 = Bb + (size_t)row0 * 512 + seg8;
  const u16* src1 = src0 + (size_t)64 * 512;
  u16* dst0 = &Bl[row0 * 40 + seg8];
  u16* dst1 = &Bl[(row0 + 64) * 40 + seg8];
  int4 p0 = *reinterpret_cast<const int4*>(src0);
  int4 p1;
  if (tid < 192) p1 = *reinterpret_cast<const int4*>(src1);
  bf16x8 afc = ld_bf8(Ar + lq * 8);
  for (int ks = 0; ks < 16; ++ks) {
    *reinterpret_cast<int4*>(dst0) = p0;
    if (tid < 192) *reinterpret_cast<int4*>(dst1) = p1;
    __syncthreads();
    bf16x8 af = afc;
    if (ks < 15) {
      p0 = *reinterpret_cast<const int4*>(src0 + (ks + 1) * 32);
      if (tid < 192) p1 = *reinterpret_cast<const int4*>(src1 + (ks + 1) * 32);
      afc = ld_bf8(Ar + (ks + 1) * 32 + lq * 8);
    }
#pragma unroll
    for (int t = 0; t < 7; ++t) {
      bf16x8 bf8 = ld_bf8(&Bl[(t * 16 + lm) * 40 + lq * 8]);
      acc[t] = MFMA16(af, bf8, acc[t]);
    }
    __syncthreads();
  }
  const int og = mt * 64 + wave * 16 + lq * 4;
  float sc[4], bi[4];
#pragma unroll
  for (int r = 0; r < 4; ++r) { sc[r] = gv[og + r] * INVS; bi[r] = bv[og + r]; }
#pragma unroll
  for (int t = 0; t < 7; ++t) {
    int j = n0 + t * 16 + lm;
    float4 bin4 = *reinterpret_cast<const float4*>(binT + ((size_t)b * 784 + j) * 512 + og);
    float4 un4 = *reinterpret_cast<const float4*>(unT + ((size_t)b * 784 + j) * 512 + og);
    float binv[4] = {bin4.x, bin4.y, bin4.z, bin4.w};
    float unv[4] = {un4.x, un4.y, un4.z, un4.w};
#pragma unroll
    for (int r = 0; r < 4; ++r) {
      float gt = 1.f / (1.f + __expf(-(acc[t][r] * sc[r] + bi[r])));
      out[((size_t)b * 512 + og + r) * 784 + j] = gt * binv[r] + unv[r];
    }
  }
}

extern "C" void kernel_launch(void* const* d_in, const int* in_sizes, int n_in,
                              void* d_out, int out_size, void* d_ws, size_t ws_size,
                              hipStream_t stream) {
  const float* x = (const float*)d_in[0];
  const float* qkv_w = (const float*)d_in[1];
  const float* g_qkv = (const float*)d_in[2];
  const float* b_qkv = (const float*)d_in[3];
  const float* g_sim = (const float*)d_in[4];
  // d_in[5] = b_sim: unused (softmax is shift-invariant per (b,g) row)
  const float* g_out = (const float*)d_in[6];
  const float* b_out = (const float*)d_in[7];
  const float* relative = (const float*)d_in[8];
  const float* xw1 = (const float*)d_in[9];
  const float* xw2 = (const float*)d_in[10];
  const float* g_x = (const float*)d_in[11];
  const float* b_x = (const float*)d_in[12];
  const float* rw = (const float*)d_in[13];
  const float* g_r = (const float*)d_in[14];
  const float* b_r = (const float*)d_in[15];
  const float* pw = (const float*)d_in[16];
  const float* g_p = (const float*)d_in[17];
  const float* b_p = (const float*)d_in[18];

  char* p = (char*)d_ws;
  auto take = [&](size_t n) { char* q = p; p += (n + 255) & ~(size_t)255; return q; };
  u16* xT = (u16*)take((size_t)8 * 784 * 512 * 2);
  u16* Wq = (u16*)take((size_t)1024 * 512 * 2);
  u16* W2 = (u16*)take((size_t)512 * 512 * 2);
  u16* Wr = (u16*)take((size_t)512 * 1024 * 2);
  u16* Wp = (u16*)take((size_t)512 * 512 * 2);
  u16* W1t = (u16*)take((size_t)294912 * 2);
  u16* relq = (u16*)take((size_t)51200 * 2);
  u16* relk = (u16*)take((size_t)51200 * 2);
  u16* relv = (u16*)take((size_t)102400 * 2);
  u16* Qs = (u16*)take((size_t)8 * 8 * 784 * 32 * 2);
  u16* Ks = (u16*)take((size_t)8 * 8 * 784 * 32 * 2);
  u16* Vs = (u16*)take(((size_t)8 * 8 * 64 * 784 + 64) * 2);  // +64 pad for K=800 reads
  u16* umid = (u16*)take((size_t)8 * 784 * 512 * 2);
  float* unT = (float*)take((size_t)8 * 784 * 512 * 4);
  float* binT = (float*)take((size_t)8 * 784 * 512 * 4);
  u16* rT = (u16*)take((size_t)8 * 784 * 512 * 2);

  k_prep<<<dim3(8096), dim3(256), 0, stream>>>(qkv_w, xw2, rw, pw, xw1, relative,
                                               Wq, W2, Wr, Wp, W1t, relq, relk, relv);
  k_transpose<<<dim3(25, 8, 8), dim3(256), 0, stream>>>(x, xT);
  k_gemm_qkv<<<dim3(7, 16, 8), dim3(256), 0, stream>>>(Wq, xT, g_qkv, b_qkv, Qs, Ks, Vs);
  k_conv1<<<dim3(7, 8, 8), dim3(256), 0, stream>>>(xT, W1t, umid);
  k_gemm_x2<<<dim3(7, 8, 8), dim3(256), 0, stream>>>(W2, umid, g_x, b_x, unT);
  k_attn<<<dim3(49, 8, 8), dim3(256), 0, stream>>>(Qs, Ks, Vs, relq, relk, relv,
                                                   g_sim, g_out, b_out, binT);
  k_gemm_rw<<<dim3(7, 8, 8), dim3(256), 0, stream>>>(Wr, unT, binT, g_r, b_r, rT);
  k_gemm_pw<<<dim3(7, 8, 8), dim3(256), 0, stream>>>(Wp, rT, g_p, b_p, binT, unT,
                                                     (float*)d_out);
}

// Round 7
// 299.198 us; speedup vs baseline: 1.1810x; 1.0059x over previous
//
#include <hip/hip_runtime.h>
#include <math.h>

// LESA block for MI355X. N=8, C=512, H=W=28 (HW=784), G=8, QKP=32, VP=64, BP=512.
// R7: kernel fusion for overlap — (prep ∥ transpose), (qkv ∥ conv1), (attn ∥ x2)
// each as one launch with block-range dispatch + shared-LDS union. Bodies are
// R6's (attn: fp16 logits in LDS; GEMMs: 1-deep register prefetch).

typedef unsigned short u16;
typedef unsigned int u32;
typedef __bf16 bf16x8 __attribute__((ext_vector_type(8)));
typedef float f32x4 __attribute__((ext_vector_type(4)));

#define INVS 0.99999500003749968f  // 1/sqrt(1+1e-5)
#define MFMA16(a, b, c) __builtin_amdgcn_mfma_f32_16x16x32_bf16(a, b, c, 0, 0, 0)

__device__ inline u16 f2bf(float f) {
  u32 u = __builtin_bit_cast(u32, f);
  return (u16)((u + 0x7fffu + ((u >> 16) & 1u)) >> 16);
}
__device__ inline bf16x8 ld_bf8(const u16* p) {
  int4 v = *reinterpret_cast<const int4*>(p);
  return __builtin_bit_cast(bf16x8, v);
}
__device__ inline bf16x8 pack8(const u16 h[8]) {
  int4 v;
  v.x = (int)((u32)h[0] | ((u32)h[1] << 16));
  v.y = (int)((u32)h[2] | ((u32)h[3] << 16));
  v.z = (int)((u32)h[4] | ((u32)h[5] << 16));
  v.w = (int)((u32)h[6] | ((u32)h[7] << 16));
  return __builtin_bit_cast(bf16x8, v);
}
__device__ inline bf16x8 zero8() {
  int4 z = {0, 0, 0, 0};
  return __builtin_bit_cast(bf16x8, z);
}
__device__ inline float bpermf(float v, int srcl) {
  return __builtin_bit_cast(float,
      __builtin_amdgcn_ds_bpermute(srcl << 2, __builtin_bit_cast(int, v)));
}

// ================= device bodies =================

__device__ void body_prep(
    int idx, const float* __restrict__ qkv_w, const float* __restrict__ xw2,
    const float* __restrict__ rw, const float* __restrict__ pw,
    const float* __restrict__ xw1, const float* __restrict__ rel,
    u16* __restrict__ Wq, u16* __restrict__ W2, u16* __restrict__ Wr,
    u16* __restrict__ Wp, u16* __restrict__ W1t, u16* __restrict__ relq,
    u16* __restrict__ relk, u16* __restrict__ relv) {
  if (idx < 524288) { Wq[idx] = f2bf(qkv_w[idx]); return; }
  idx -= 524288;
  if (idx < 262144) { W2[idx] = f2bf(xw2[idx]); return; }
  idx -= 262144;
  if (idx < 524288) { Wr[idx] = f2bf(rw[idx]); return; }
  idx -= 524288;
  if (idx < 262144) { Wp[idx] = f2bf(pw[idx]); return; }
  idx -= 262144;
  if (idx < 294912) {  // W1t[(g*9+k9)*64 + oc][ic] = xw1[g*64+oc][ic][kh][kw]
    int gk = idx >> 12, rem = idx & 4095, oc = rem >> 6, ic = rem & 63;
    int g = gk / 9, k9 = gk % 9;
    W1t[idx] = f2bf(xw1[(((g * 64 + oc) * 64) + ic) * 9 + k9]);
    return;
  }
  idx -= 294912;
  if (idx < 51200) {  // relq[t][c] = relative[c][t], t<1600 (pad 0)
    int t = idx >> 5, c = idx & 31;
    relq[idx] = (t < 1567) ? f2bf(rel[c * 1567 + t]) : (u16)0;
    return;
  }
  idx -= 51200;
  if (idx < 51200) {
    int t = idx >> 5, c = idx & 31;
    relk[idx] = (t < 1567) ? f2bf(rel[(32 + c) * 1567 + t]) : (u16)0;
    return;
  }
  idx -= 51200;
  if (idx < 102400) {  // relv[c][t] (c<64, t<1600 pad 0)
    int c = idx / 1600, t = idx % 1600;
    relv[idx] = (t < 1567) ? f2bf(rel[(64 + c) * 1567 + t]) : (u16)0;
    return;
  }
}

__device__ void body_transpose(int bx, int by, int bz, const float* __restrict__ x,
                               u16* __restrict__ xT, char* smem) {
  const int b = bz, c0 = by * 64, n0 = bx * 32;
  const int tid = threadIdx.x;
  u16(*tl)[36] = reinterpret_cast<u16(*)[36]>(smem);
#pragma unroll
  for (int h = 0; h < 2; ++h) {
    int cl = (tid >> 3) + h * 32;
    int n4 = (tid & 7) * 4;
    float4 v = {0.f, 0.f, 0.f, 0.f};
    if (n0 + n4 + 3 < 784)
      v = *reinterpret_cast<const float4*>(x + ((size_t)b * 512 + c0 + cl) * 784 + n0 + n4);
    u32 lo = (u32)f2bf(v.x) | ((u32)f2bf(v.y) << 16);
    u32 hi = (u32)f2bf(v.z) | ((u32)f2bf(v.w) << 16);
    *reinterpret_cast<int2*>(&tl[cl][n4]) = make_int2((int)lo, (int)hi);
  }
  __syncthreads();
  int nl = tid >> 3, c8 = (tid & 7) * 8;
  if (n0 + nl < 784) {
    u16 h[8];
#pragma unroll
    for (int e = 0; e < 8; ++e) h[e] = tl[c8 + e][nl];
    *reinterpret_cast<int4*>(xT + ((size_t)b * 784 + n0 + nl) * 512 + c0 + c8) =
        __builtin_bit_cast(int4, pack8(h));
  }
}

__device__ void body_qkv(int bx, int by, int bz,
                         const u16* __restrict__ W, const u16* __restrict__ xT,
                         const float* __restrict__ gq, const float* __restrict__ bq,
                         u16* __restrict__ Qs, u16* __restrict__ Ks,
                         u16* __restrict__ Vs, char* smem) {
  const int b = bz, mt = by, n0 = bx * 112;
  const int tid = threadIdx.x, lane = tid & 63, wave = tid >> 6;
  const int lm = lane & 15, lq = lane >> 4;
  u16* Bl = reinterpret_cast<u16*>(smem);
  f32x4 zf = {0.f, 0.f, 0.f, 0.f};
  f32x4 acc[7];
#pragma unroll
  for (int t = 0; t < 7; ++t) acc[t] = zf;
  const u16* Bb = xT + ((size_t)b * 784 + n0) * 512;
  const u16* Ar = W + (size_t)(mt * 64 + wave * 16 + lm) * 512;
  const int row0 = tid >> 2, seg8 = (tid & 3) * 8;
  const u16* src0 = Bb + (size_t)row0 * 512 + seg8;
  const u16* src1 = src0 + (size_t)64 * 512;
  u16* dst0 = &Bl[row0 * 40 + seg8];
  u16* dst1 = &Bl[(row0 + 64) * 40 + seg8];
  int4 p0 = *reinterpret_cast<const int4*>(src0);
  int4 p1;
  if (tid < 192) p1 = *reinterpret_cast<const int4*>(src1);
  bf16x8 afc = ld_bf8(Ar + lq * 8);
  for (int ks = 0; ks < 16; ++ks) {
    *reinterpret_cast<int4*>(dst0) = p0;
    if (tid < 192) *reinterpret_cast<int4*>(dst1) = p1;
    __syncthreads();
    bf16x8 af = afc;
    if (ks < 15) {
      p0 = *reinterpret_cast<const int4*>(src0 + (ks + 1) * 32);
      if (tid < 192) p1 = *reinterpret_cast<const int4*>(src1 + (ks + 1) * 32);
      afc = ld_bf8(Ar + (ks + 1) * 32 + lq * 8);
    }
#pragma unroll
    for (int t = 0; t < 7; ++t) {
      bf16x8 bf8 = ld_bf8(&Bl[(t * 16 + lm) * 40 + lq * 8]);
      acc[t] = MFMA16(af, bf8, acc[t]);
    }
    __syncthreads();
  }
  const int og = mt * 64 + wave * 16 + lq * 4;
  float sc[4], bi[4];
#pragma unroll
  for (int r = 0; r < 4; ++r) { sc[r] = gq[og + r] * INVS; bi[r] = bq[og + r]; }
  const int g = og >> 7, r128 = og & 127;
  const size_t bg = (size_t)b * 8 + g;
#pragma unroll
  for (int t = 0; t < 7; ++t) {
    int j = n0 + t * 16 + lm;
    u16 h[4];
#pragma unroll
    for (int r = 0; r < 4; ++r) h[r] = f2bf(acc[t][r] * sc[r] + bi[r]);
    if (r128 < 64) {
      u16* dst = (r128 < 32) ? Qs : Ks;
      int c = r128 & 31;
      u32 lo = (u32)h[0] | ((u32)h[1] << 16);
      u32 hi = (u32)h[2] | ((u32)h[3] << 16);
      *reinterpret_cast<int2*>(dst + (bg * 784 + j) * 32 + c) = make_int2((int)lo, (int)hi);
    } else {
      int c = r128 - 64;
#pragma unroll
      for (int r = 0; r < 4; ++r) Vs[(bg * 64 + c + r) * 784 + j] = h[r];
    }
  }
}

__device__ void body_conv1(int bx, int by, int bz, const u16* __restrict__ xT,
                           const u16* __restrict__ W1t, u16* __restrict__ umid,
                           char* smem) {
  const int b = bz, g = by, n0 = bx * 112;
  const int tid = threadIdx.x, lane = tid & 63, wave = tid >> 6;
  const int lm = lane & 15, lq = lane >> 4;
  u16* xl = reinterpret_cast<u16*>(smem);  // 170*72
  for (int u = tid; u < 1360; u += 256) {
    int row = u >> 3, seg = u & 7;
    int ng = n0 - 29 + row;
    int4 v = {0, 0, 0, 0};
    if (ng >= 0 && ng < 784)
      v = *reinterpret_cast<const int4*>(xT + ((size_t)b * 784 + ng) * 512 + g * 64 + seg * 8);
    *reinterpret_cast<int4*>(&xl[row * 72 + seg * 8]) = v;
  }
  __syncthreads();
  f32x4 zf = {0.f, 0.f, 0.f, 0.f};
  f32x4 acc[7];
#pragma unroll
  for (int t = 0; t < 7; ++t) acc[t] = zf;
  const u16* Wg = W1t + (size_t)g * 9 * 4096;
#pragma unroll
  for (int k9 = 0; k9 < 9; ++k9) {
    const int dh = k9 / 3 - 1, dw = k9 % 3 - 1;
#pragma unroll
    for (int ks = 0; ks < 2; ++ks) {
      bf16x8 af = ld_bf8(Wg + (k9 * 64 + wave * 16 + lm) * 64 + ks * 32 + lq * 8);
#pragma unroll
      for (int t = 0; t < 7; ++t) {
        int n = n0 + t * 16 + lm;
        int ww = n % 28 + dw;
        bf16x8 bf8;
        if (ww >= 0 && ww < 28)
          bf8 = ld_bf8(&xl[(t * 16 + lm + dh * 28 + dw + 29) * 72 + ks * 32 + lq * 8]);
        else
          bf8 = zero8();
        acc[t] = MFMA16(af, bf8, acc[t]);
      }
    }
  }
  const int oc4 = g * 64 + wave * 16 + lq * 4;
#pragma unroll
  for (int t = 0; t < 7; ++t) {
    int j = n0 + t * 16 + lm;
    u16 h[4];
#pragma unroll
    for (int r = 0; r < 4; ++r) h[r] = f2bf(acc[t][r]);
    u32 lo = (u32)h[0] | ((u32)h[1] << 16);
    u32 hi = (u32)h[2] | ((u32)h[3] << 16);
    *reinterpret_cast<int2*>(umid + ((size_t)b * 784 + j) * 512 + oc4) = make_int2((int)lo, (int)hi);
  }
}

__device__ void body_x2(int bx, int by, int bz,
                        const u16* __restrict__ W, const u16* __restrict__ Bsrc,
                        const float* __restrict__ gv, const float* __restrict__ bv,
                        float* __restrict__ outT, char* smem) {
  const int b = bz, mt = by, n0 = bx * 112;
  const int tid = threadIdx.x, lane = tid & 63, wave = tid >> 6;
  const int lm = lane & 15, lq = lane >> 4;
  u16* Bl = reinterpret_cast<u16*>(smem);
  f32x4 zf = {0.f, 0.f, 0.f, 0.f};
  f32x4 acc[7];
#pragma unroll
  for (int t = 0; t < 7; ++t) acc[t] = zf;
  const u16* Bb = Bsrc + ((size_t)b * 784 + n0) * 512;
  const u16* Ar = W + (size_t)(mt * 64 + wave * 16 + lm) * 512;
  const int row0 = tid >> 2, seg8 = (tid & 3) * 8;
  const u16* src0 = Bb + (size_t)row0 * 512 + seg8;
  const u16* src1 = src0 + (size_t)64 * 512;
  u16* dst0 = &Bl[row0 * 40 + seg8];
  u16* dst1 = &Bl[(row0 + 64) * 40 + seg8];
  int4 p0 = *reinterpret_cast<const int4*>(src0);
  int4 p1;
  if (tid < 192) p1 = *reinterpret_cast<const int4*>(src1);
  bf16x8 afc = ld_bf8(Ar + lq * 8);
  for (int ks = 0; ks < 16; ++ks) {
    *reinterpret_cast<int4*>(dst0) = p0;
    if (tid < 192) *reinterpret_cast<int4*>(dst1) = p1;
    __syncthreads();
    bf16x8 af = afc;
    if (ks < 15) {
      p0 = *reinterpret_cast<const int4*>(src0 + (ks + 1) * 32);
      if (tid < 192) p1 = *reinterpret_cast<const int4*>(src1 + (ks + 1) * 32);
      afc = ld_bf8(Ar + (ks + 1) * 32 + lq * 8);
    }
#pragma unroll
    for (int t = 0; t < 7; ++t) {
      bf16x8 bf8 = ld_bf8(&Bl[(t * 16 + lm) * 40 + lq * 8]);
      acc[t] = MFMA16(af, bf8, acc[t]);
    }
    __syncthreads();
  }
  const int og = mt * 64 + wave * 16 + lq * 4;
  float sc[4], bi[4];
#pragma unroll
  for (int r = 0; r < 4; ++r) { sc[r] = gv[og + r] * INVS; bi[r] = bv[og + r]; }
#pragma unroll
  for (int t = 0; t < 7; ++t) {
    int j = n0 + t * 16 + lm;
    float4 o4;
    o4.x = acc[t][0] * sc[0] + bi[0];
    o4.y = acc[t][1] * sc[1] + bi[1];
    o4.z = acc[t][2] * sc[2] + bi[2];
    o4.w = acc[t][3] * sc[3] + bi[3];
    *reinterpret_cast<float4*>(outT + ((size_t)b * 784 + j) * 512 + og) = o4;
  }
}

// attn smem layout (bytes): Pl u16[16+16*872] @0 (27936), KRs f32[4*16*34] @27936
// (8704), WM f32[64] @36640 (256), rstat f32[16] @36896 (64). Total 36960.
__device__ void body_attn(int bx, int by, int bz,
                          const u16* __restrict__ Qs, const u16* __restrict__ Ks,
                          const u16* __restrict__ Vs, const u16* __restrict__ relq,
                          const u16* __restrict__ relk, const u16* __restrict__ relv,
                          const float* __restrict__ g_sim, const float* __restrict__ g_out,
                          const float* __restrict__ b_out, float* __restrict__ binT,
                          char* smem) {
  const int b = bz, g = by, i0 = bx * 16;
  const int tid = threadIdx.x, lane = tid & 63, wave = tid >> 6;
  const int lm = lane & 15, lq = lane >> 4;
  u16* Pl = reinterpret_cast<u16*>(smem);
  float* KRs = reinterpret_cast<float*>(smem + 27936);  // [w][m][c34] -> (w*16+m)*34+c
  float* WM = reinterpret_cast<float*>(smem + 36640);   // [w][row] -> w*16+row
  float* rstat = reinterpret_cast<float*>(smem + 36896);
  // zero header [0,16) and right pads [784,872) of each row
  for (int u = tid; u < 1424; u += 256) {
    int idx = (u < 16) ? u : (16 + ((u - 16) / 88) * 872 + 784 + (u - 16) % 88);
    Pl[idx] = 0;
  }
  const float s0 = g_sim[g] * INVS, s1 = g_sim[8 + g] * INVS, s2 = g_sim[16 + g] * INVS;
  const size_t bg = (size_t)b * 8 + g;
  const u16* Qb = Qs + bg * 784 * 32;
  const u16* Kb = Ks + bg * 784 * 32;
  const u16* Vb = Vs + bg * 64 * 784;
  const bf16x8 aq = ld_bf8(Qb + (i0 + lm) * 32 + lq * 8);
  const f32x4 zf = {0.f, 0.f, 0.f, 0.f};
  // ---- phase 1: logits -> fp16 LDS; wave owns j-tiles wave, wave+4, ... ----
  float vmax[4] = {-1e30f, -1e30f, -1e30f, -1e30f};
  bf16x8 kfc, bq0c, bq1c, bk0c, bk1c;
  {
    const int j0 = wave * 16;
    const int d0 = 768 + i0 - j0, e0 = 768 + j0 - i0;
    kfc = ld_bf8(Kb + (j0 + lm) * 32 + lq * 8);
    bq0c = ld_bf8(relq + (d0 + lm) * 32 + lq * 8);
    bq1c = ld_bf8(relq + (d0 + 16 + lm) * 32 + lq * 8);
    bk0c = ld_bf8(relk + (e0 + lm) * 32 + lq * 8);
    bk1c = ld_bf8(relk + (e0 + 16 + lm) * 32 + lq * 8);
  }
  int jt = wave;
  for (int rr = 0; rr < 13; ++rr) {
    const int jtn = jt + 4;
    bf16x8 kfn = kfc, bq0n = bq0c, bq1n = bq1c, bk0n = bk0c, bk1n = bk1c;
    if (jtn < 49) {
      const int j0n = jtn * 16;
      const int d0 = 768 + i0 - j0n, e0 = 768 + j0n - i0;
      kfn = ld_bf8(Kb + (j0n + lm) * 32 + lq * 8);
      bq0n = ld_bf8(relq + (d0 + lm) * 32 + lq * 8);
      bq1n = ld_bf8(relq + (d0 + 16 + lm) * 32 + lq * 8);
      bk0n = ld_bf8(relk + (e0 + lm) * 32 + lq * 8);
      bk1n = ld_bf8(relk + (e0 + 16 + lm) * 32 + lq * 8);
    }
    if (jt < 49) {
      const int j0 = jt * 16;
      f32x4 aqk = MFMA16(aq, kfc, zf);      // qk[i][j]
      f32x4 q0 = MFMA16(aq, bq0c, zf);      // QRt[i][d] cols 0..15
      f32x4 q1 = MFMA16(aq, bq1c, zf);      // cols 16..31
      f32x4 k0 = MFMA16(kfc, bk0c, zf);     // KRt[j][s] cols 0..15
      f32x4 k1 = MFMA16(kfc, bk1c, zf);
#pragma unroll
      for (int r = 0; r < 4; ++r) {
        int m = lq * 4 + r;
        KRs[(wave * 16 + m) * 34 + lm] = k0[r];
        KRs[(wave * 16 + m) * 34 + 16 + lm] = k1[r];
      }
      // per-wave LDS RAW: compiler inserts lgkmcnt wait, no barrier needed
#pragma unroll
      for (int r = 0; r < 4; ++r) {
        int m = lq * 4 + r, n = lm;
        int c = m - n + 15;  // qr gather col
        int srcl = (c & 15) | (lane & 48);
        float t0 = bpermf(q0[r], srcl), t1 = bpermf(q1[r], srcl);
        float qv = (c & 16) ? t1 : t0;
        float kv = KRs[(wave * 16 + n) * 34 + (n - m + 15)];
        float val = aqk[r] * s0 + qv * s1 + kv * s2;  // b_sim drops (shift-invariant)
        vmax[r] = fmaxf(vmax[r], val);
        _Float16 hv = (_Float16)val;
        Pl[16 + m * 872 + j0 + n] = __builtin_bit_cast(u16, hv);
      }
    }
    jt = jtn;
    kfc = kfn; bq0c = bq0n; bq1c = bq1n; bk0c = bk0n; bk1c = bk1n;
  }
  // wave-local row max reduce over n (lm bits)
#pragma unroll
  for (int r = 0; r < 4; ++r) {
#pragma unroll
    for (int d = 1; d < 16; d <<= 1) vmax[r] = fmaxf(vmax[r], __shfl_xor(vmax[r], d, 64));
  }
  if (lm == 0) {
#pragma unroll
    for (int r = 0; r < 4; ++r) WM[wave * 16 + lq * 4 + r] = vmax[r];
  }
  __syncthreads();
  // ---- phase 2: softmax, fp16 -> bf16 P~ IN-PLACE (same index, same size) ----
  {
    const int row = tid >> 4, sub = tid & 15;
    u16* Pr = &Pl[16 + row * 872];
    float gmax = fmaxf(fmaxf(WM[row], WM[16 + row]), fmaxf(WM[32 + row], WM[48 + row]));
    float sm = 0.f;
    for (int k = 0; k < 49; ++k) {
      int j = sub + 16 * k;
      _Float16 hv = __builtin_bit_cast(_Float16, Pr[j]);
      float e = __expf((float)hv - gmax);
      sm += e;
      Pr[j] = f2bf(e);
    }
#pragma unroll
    for (int d = 1; d < 16; d <<= 1) sm += __shfl_xor(sm, d, 64);
    if (sub == 0) rstat[row] = 1.0f / sm;
  }
  __syncthreads();
  // ---- phase 3: PV; wave = c-chunk of 16; sv = P~ @ V^T, sve = Psh @ relv^T ----
  f32x4 accV = zf, accE = zf;
  const int coff = wave * 16;
  const u16* Vr = Vb + (size_t)(coff + lm) * 784;
  const u16* Rr = relv + (size_t)(coff + lm) * 1600 + i0;
  const u16* Prow = &Pl[16 + lm * 872];
  for (int ks = 0; ks < 25; ++ks) {
    bf16x8 ap = ld_bf8(Prow + ks * 32 + lq * 8);  // cols>=784 read zero pad
    bf16x8 bv = ld_bf8(Vr + ks * 32 + lq * 8);
    accV = MFMA16(ap, bv, accV);
    const int base = 783 + lm - ks * 32 - lq * 8;  // Psh gather; pads/header give 0
    u16 h[8];
#pragma unroll
    for (int e = 0; e < 8; ++e) h[e] = Prow[base - e];
    bf16x8 ash = pack8(h);
    bf16x8 br = ld_bf8(Rr + ks * 32 + lq * 8);
    accE = MFMA16(ash, br, accE);
  }
  // ---- epilogue: binary[b, g*64+c, i] = bn(sv)+bn(sve), write (i, c) layout ----
  const int c = coff + lm;
  const int oi = g * 128 + 2 * c;
  const float so0 = g_out[oi] * INVS, bo0 = b_out[oi];
  const float so1 = g_out[oi + 1] * INVS, bo1 = b_out[oi + 1];
#pragma unroll
  for (int r = 0; r < 4; ++r) {
    int row = lq * 4 + r;
    float rl = rstat[row];
    float val = accV[r] * rl * so0 + bo0 + accE[r] * rl * so1 + bo1;
    binT[((size_t)b * 784 + i0 + row) * 512 + g * 64 + c] = val;
  }
}

// ================= fused kernels =================

// prep (8096 blocks) ∥ transpose (1600 blocks)
__global__ __launch_bounds__(256) void k_pt(
    const float* __restrict__ x, u16* __restrict__ xT,
    const float* __restrict__ qkv_w, const float* __restrict__ xw2,
    const float* __restrict__ rw, const float* __restrict__ pw,
    const float* __restrict__ xw1, const float* __restrict__ rel,
    u16* __restrict__ Wq, u16* __restrict__ W2, u16* __restrict__ Wr,
    u16* __restrict__ Wp, u16* __restrict__ W1t, u16* __restrict__ relq,
    u16* __restrict__ relk, u16* __restrict__ relv) {
  __shared__ __align__(16) char smem[4608];
  const int bid = blockIdx.x;
  if (bid < 1600) {
    body_transpose(bid % 25, (bid / 25) % 8, bid / 200, x, xT, smem);
  } else {
    body_prep((bid - 1600) * 256 + threadIdx.x, qkv_w, xw2, rw, pw, xw1, rel,
              Wq, W2, Wr, Wp, W1t, relq, relk, relv);
  }
}

// conv1 (448 blocks) ∥ qkv (896 blocks)
__global__ __launch_bounds__(256) void k_qc(
    const u16* __restrict__ Wq, const u16* __restrict__ xT,
    const float* __restrict__ gq, const float* __restrict__ bq,
    u16* __restrict__ Qs, u16* __restrict__ Ks, u16* __restrict__ Vs,
    const u16* __restrict__ W1t, u16* __restrict__ umid) {
  __shared__ __align__(16) char smem[24480];
  const int bid = blockIdx.x;
  if (bid < 448) {
    body_conv1(bid % 7, (bid / 7) % 8, bid / 56, xT, W1t, umid, smem);
  } else {
    const int q = bid - 448;
    body_qkv(q % 7, (q / 7) % 16, q / 112, Wq, xT, gq, bq, Qs, Ks, Vs, smem);
  }
}

// x2 (448 blocks) ∥ attn (3136 blocks)
__global__ __launch_bounds__(256) void k_ax(
    const u16* __restrict__ W2, const u16* __restrict__ umid,
    const float* __restrict__ g_x, const float* __restrict__ b_x,
    float* __restrict__ unT,
    const u16* __restrict__ Qs, const u16* __restrict__ Ks, const u16* __restrict__ Vs,
    const u16* __restrict__ relq, const u16* __restrict__ relk,
    const u16* __restrict__ relv, const float* __restrict__ g_sim,
    const float* __restrict__ g_out, const float* __restrict__ b_out,
    float* __restrict__ binT) {
  __shared__ __align__(16) char smem[36960];
  const int bid = blockIdx.x;
  if (bid < 448) {
    body_x2(bid % 7, (bid / 7) % 8, bid / 56, W2, umid, g_x, b_x, unT, smem);
  } else {
    const int a = bid - 448;
    body_attn(a % 49, (a / 49) % 8, a / 392, Qs, Ks, Vs, relq, relk, relv,
              g_sim, g_out, b_out, binT, smem);
  }
}

// ---------------- rw GEMM: relu(concat(unary,binary)) -> relu(bn) -> rT bf16 ----------------
__global__ __launch_bounds__(256) void k_gemm_rw(
    const u16* __restrict__ W, const float* __restrict__ unT, const float* __restrict__ binT,
    const float* __restrict__ gv, const float* __restrict__ bv, u16* __restrict__ rT) {
  const int b = blockIdx.z, mt = blockIdx.y, n0 = blockIdx.x * 112;
  const int tid = threadIdx.x, lane = tid & 63, wave = tid >> 6;
  const int lm = lane & 15, lq = lane >> 4;
  __shared__ __align__(16) u16 Bl[112 * 40];
  f32x4 zf = {0.f, 0.f, 0.f, 0.f};
  f32x4 acc[7];
#pragma unroll
  for (int t = 0; t < 7; ++t) acc[t] = zf;
  const u16* Ar = W + (size_t)(mt * 64 + wave * 16 + lm) * 1024;
  const int row0 = tid >> 2, seg8 = (tid & 3) * 8;
  const size_t off0 = ((size_t)b * 784 + n0 + row0) * 512 + seg8;
  const size_t off1 = off0 + (size_t)64 * 512;
  u16* dst0 = &Bl[row0 * 40 + seg8];
  u16* dst1 = &Bl[(row0 + 64) * 40 + seg8];
  auto ldrow = [](const float* sp, float4& a, float4& b) {
    a = *reinterpret_cast<const float4*>(sp);
    b = *reinterpret_cast<const float4*>(sp + 4);
  };
  auto cvt_store = [](u16* dst, float4 a, float4 b) {
    u16 h[8] = {f2bf(fmaxf(a.x, 0.f)), f2bf(fmaxf(a.y, 0.f)),
                f2bf(fmaxf(a.z, 0.f)), f2bf(fmaxf(a.w, 0.f)),
                f2bf(fmaxf(b.x, 0.f)), f2bf(fmaxf(b.y, 0.f)),
                f2bf(fmaxf(b.z, 0.f)), f2bf(fmaxf(b.w, 0.f))};
    *reinterpret_cast<int4*>(dst) = __builtin_bit_cast(int4, pack8(h));
  };
  float4 a0, b0, a1, b1;
  ldrow(unT + off0, a0, b0);
  if (tid < 192) ldrow(unT + off1, a1, b1);
  bf16x8 afc = ld_bf8(Ar + lq * 8);
  for (int ks = 0; ks < 32; ++ks) {
    cvt_store(dst0, a0, b0);
    if (tid < 192) cvt_store(dst1, a1, b1);
    __syncthreads();
    bf16x8 af = afc;
    if (ks < 31) {
      const int ksn = ks + 1;
      const float* sb = (ksn < 16) ? unT : binT;
      const int k0 = (ksn & 15) * 32;
      ldrow(sb + off0 + k0, a0, b0);
      if (tid < 192) ldrow(sb + off1 + k0, a1, b1);
      afc = ld_bf8(Ar + ksn * 32 + lq * 8);
    }
#pragma unroll
    for (int t = 0; t < 7; ++t) {
      bf16x8 bf8 = ld_bf8(&Bl[(t * 16 + lm) * 40 + lq * 8]);
      acc[t] = MFMA16(af, bf8, acc[t]);
    }
    __syncthreads();
  }
  const int og = mt * 64 + wave * 16 + lq * 4;
  float sc[4], bi[4];
#pragma unroll
  for (int r = 0; r < 4; ++r) { sc[r] = gv[og + r] * INVS; bi[r] = bv[og + r]; }
#pragma unroll
  for (int t = 0; t < 7; ++t) {
    int j = n0 + t * 16 + lm;
    u16 h[4];
#pragma unroll
    for (int r = 0; r < 4; ++r) h[r] = f2bf(fmaxf(acc[t][r] * sc[r] + bi[r], 0.f));
    u32 lo = (u32)h[0] | ((u32)h[1] << 16);
    u32 hi = (u32)h[2] | ((u32)h[3] << 16);
    *reinterpret_cast<int2*>(rT + ((size_t)b * 784 + j) * 512 + og) = make_int2((int)lo, (int)hi);
  }
}

// ---------------- pw GEMM + sigmoid gate + final fuse -> d_out ----------------
__global__ __launch_bounds__(256) void k_gemm_pw(
    const u16* __restrict__ W, const u16* __restrict__ rT,
    const float* __restrict__ gv, const float* __restrict__ bv,
    const float* __restrict__ binT, const float* __restrict__ unT,
    float* __restrict__ out) {
  const int b = blockIdx.z, mt = blockIdx.y, n0 = blockIdx.x * 112;
  const int tid = threadIdx.x, lane = tid & 63, wave = tid >> 6;
  const int lm = lane & 15, lq = lane >> 4;
  __shared__ __align__(16) u16 Bl[112 * 40];
  f32x4 zf = {0.f, 0.f, 0.f, 0.f};
  f32x4 acc[7];
#pragma unroll
  for (int t = 0; t < 7; ++t) acc[t] = zf;
  const u16* Bb = rT + ((size_t)b * 784 + n0) * 512;
  const u16* Ar = W + (size_t)(mt * 64 + wave * 16 + lm) * 512;
  const int row0 = tid >> 2, seg8 = (tid & 3) * 8;
  const u16* src0 = Bb + (size_t)row0 * 512 + seg8;
  const u16* src1 = src0 + (size_t)64 * 512;
  u16* dst0 = &Bl[row0 * 40 + seg8];
  u16* dst1 = &Bl[(row0 + 64) * 40 + seg8];
  int4 p0 = *reinterpret_cast<const int4*>(src0);
  int4 p1;
  if (tid < 192) p1 = *reinterpret_cast<const int4*>(src1);
  bf16x8 afc = ld_bf8(Ar + lq * 8);
  for (int ks = 0; ks < 16; ++ks) {
    *reinterpret_cast<int4*>(dst0) = p0;
    if (tid < 192) *reinterpret_cast<int4*>(dst1) = p1;
    __syncthreads();
    bf16x8 af = afc;
    if (ks < 15) {
      p0 = *reinterpret_cast<const int4*>(src0 + (ks + 1) * 32);
      if (tid < 192) p1 = *reinterpret_cast<const int4*>(src1 + (ks + 1) * 32);
      afc = ld_bf8(Ar + (ks + 1) * 32 + lq * 8);
    }
#pragma unroll
    for (int t = 0; t < 7; ++t) {
      bf16x8 bf8 = ld_bf8(&Bl[(t * 16 + lm) * 40 + lq * 8]);
      acc[t] = MFMA16(af, bf8, acc[t]);
    }
    __syncthreads();
  }
  const int og = mt * 64 + wave * 16 + lq * 4;
  float sc[4], bi[4];
#pragma unroll
  for (int r = 0; r < 4; ++r) { sc[r] = gv[og + r] * INVS; bi[r] = bv[og + r]; }
#pragma unroll
  for (int t = 0; t < 7; ++t) {
    int j = n0 + t * 16 + lm;
    float4 bin4 = *reinterpret_cast<const float4*>(binT + ((size_t)b * 784 + j) * 512 + og);
    float4 un4 = *reinterpret_cast<const float4*>(unT + ((size_t)b * 784 + j) * 512 + og);
    float binv[4] = {bin4.x, bin4.y, bin4.z, bin4.w};
    float unv[4] = {un4.x, un4.y, un4.z, un4.w};
#pragma unroll
    for (int r = 0; r < 4; ++r) {
      float gt = 1.f / (1.f + __expf(-(acc[t][r] * sc[r] + bi[r])));
      out[((size_t)b * 512 + og + r) * 784 + j] = gt * binv[r] + unv[r];
    }
  }
}

extern "C" void kernel_launch(void* const* d_in, const int* in_sizes, int n_in,
                              void* d_out, int out_size, void* d_ws, size_t ws_size,
                              hipStream_t stream) {
  const float* x = (const float*)d_in[0];
  const float* qkv_w = (const float*)d_in[1];
  const float* g_qkv = (const float*)d_in[2];
  const float* b_qkv = (const float*)d_in[3];
  const float* g_sim = (const float*)d_in[4];
  // d_in[5] = b_sim: unused (softmax is shift-invariant per (b,g) row)
  const float* g_out = (const float*)d_in[6];
  const float* b_out = (const float*)d_in[7];
  const float* relative = (const float*)d_in[8];
  const float* xw1 = (const float*)d_in[9];
  const float* xw2 = (const float*)d_in[10];
  const float* g_x = (const float*)d_in[11];
  const float* b_x = (const float*)d_in[12];
  const float* rw = (const float*)d_in[13];
  const float* g_r = (const float*)d_in[14];
  const float* b_r = (const float*)d_in[15];
  const float* pw = (const float*)d_in[16];
  const float* g_p = (const float*)d_in[17];
  const float* b_p = (const float*)d_in[18];

  char* p = (char*)d_ws;
  auto take = [&](size_t n) { char* q = p; p += (n + 255) & ~(size_t)255; return q; };
  u16* xT = (u16*)take((size_t)8 * 784 * 512 * 2);
  u16* Wq = (u16*)take((size_t)1024 * 512 * 2);
  u16* W2 = (u16*)take((size_t)512 * 512 * 2);
  u16* Wr = (u16*)take((size_t)512 * 1024 * 2);
  u16* Wp = (u16*)take((size_t)512 * 512 * 2);
  u16* W1t = (u16*)take((size_t)294912 * 2);
  u16* relq = (u16*)take((size_t)51200 * 2);
  u16* relk = (u16*)take((size_t)51200 * 2);
  u16* relv = (u16*)take((size_t)102400 * 2);
  u16* Qs = (u16*)take((size_t)8 * 8 * 784 * 32 * 2);
  u16* Ks = (u16*)take((size_t)8 * 8 * 784 * 32 * 2);
  u16* Vs = (u16*)take(((size_t)8 * 8 * 64 * 784 + 64) * 2);  // +64 pad for K=800 reads
  u16* umid = (u16*)take((size_t)8 * 784 * 512 * 2);
  float* unT = (float*)take((size_t)8 * 784 * 512 * 4);
  float* binT = (float*)take((size_t)8 * 784 * 512 * 4);
  u16* rT = (u16*)take((size_t)8 * 784 * 512 * 2);

  k_pt<<<dim3(9696), dim3(256), 0, stream>>>(x, xT, qkv_w, xw2, rw, pw, xw1, relative,
                                             Wq, W2, Wr, Wp, W1t, relq, relk, relv);
  k_qc<<<dim3(1344), dim3(256), 0, stream>>>(Wq, xT, g_qkv, b_qkv, Qs, Ks, Vs, W1t, umid);
  k_ax<<<dim3(3584), dim3(256), 0, stream>>>(W2, umid, g_x, b_x, unT, Qs, Ks, Vs,
                                             relq, relk, relv, g_sim, g_out, b_out, binT);
  k_gemm_rw<<<dim3(7, 8, 8), dim3(256), 0, stream>>>(Wr, unT, binT, g_r, b_r, rT);
  k_gemm_pw<<<dim3(7, 8, 8), dim3(256), 0, stream>>>(Wp, rT, g_p, b_p, binT, unT,
                                                     (float*)d_out);
}

// Round 8
// 290.700 us; speedup vs baseline: 1.2156x; 1.0292x over previous
//
#include <hip/hip_runtime.h>
#include <math.h>

// LESA block for MI355X. N=8, C=512, H=W=28 (HW=784), G=8, QKP=32, VP=64, BP=512.
// R8: (a) body_x2 de-prefetched (low VGPR) so fused k_ax stays ~64 VGPR and
// attn keeps 4 blocks/CU. (b) producers emit relu'd bf16 copies (unTh/binTh);
// k_gemm_rw becomes a pure bf16 GEMM (no f32 staging, no relu/cvt in loop).

typedef unsigned short u16;
typedef unsigned int u32;
typedef __bf16 bf16x8 __attribute__((ext_vector_type(8)));
typedef float f32x4 __attribute__((ext_vector_type(4)));

#define INVS 0.99999500003749968f  // 1/sqrt(1+1e-5)
#define MFMA16(a, b, c) __builtin_amdgcn_mfma_f32_16x16x32_bf16(a, b, c, 0, 0, 0)

__device__ inline u16 f2bf(float f) {
  u32 u = __builtin_bit_cast(u32, f);
  return (u16)((u + 0x7fffu + ((u >> 16) & 1u)) >> 16);
}
__device__ inline bf16x8 ld_bf8(const u16* p) {
  int4 v = *reinterpret_cast<const int4*>(p);
  return __builtin_bit_cast(bf16x8, v);
}
__device__ inline bf16x8 pack8(const u16 h[8]) {
  int4 v;
  v.x = (int)((u32)h[0] | ((u32)h[1] << 16));
  v.y = (int)((u32)h[2] | ((u32)h[3] << 16));
  v.z = (int)((u32)h[4] | ((u32)h[5] << 16));
  v.w = (int)((u32)h[6] | ((u32)h[7] << 16));
  return __builtin_bit_cast(bf16x8, v);
}
__device__ inline bf16x8 zero8() {
  int4 z = {0, 0, 0, 0};
  return __builtin_bit_cast(bf16x8, z);
}
__device__ inline float bpermf(float v, int srcl) {
  return __builtin_bit_cast(float,
      __builtin_amdgcn_ds_bpermute(srcl << 2, __builtin_bit_cast(int, v)));
}

// ================= device bodies =================

__device__ void body_prep(
    int idx, const float* __restrict__ qkv_w, const float* __restrict__ xw2,
    const float* __restrict__ rw, const float* __restrict__ pw,
    const float* __restrict__ xw1, const float* __restrict__ rel,
    u16* __restrict__ Wq, u16* __restrict__ W2, u16* __restrict__ Wr,
    u16* __restrict__ Wp, u16* __restrict__ W1t, u16* __restrict__ relq,
    u16* __restrict__ relk, u16* __restrict__ relv) {
  if (idx < 524288) { Wq[idx] = f2bf(qkv_w[idx]); return; }
  idx -= 524288;
  if (idx < 262144) { W2[idx] = f2bf(xw2[idx]); return; }
  idx -= 262144;
  if (idx < 524288) { Wr[idx] = f2bf(rw[idx]); return; }
  idx -= 524288;
  if (idx < 262144) { Wp[idx] = f2bf(pw[idx]); return; }
  idx -= 262144;
  if (idx < 294912) {  // W1t[(g*9+k9)*64 + oc][ic] = xw1[g*64+oc][ic][kh][kw]
    int gk = idx >> 12, rem = idx & 4095, oc = rem >> 6, ic = rem & 63;
    int g = gk / 9, k9 = gk % 9;
    W1t[idx] = f2bf(xw1[(((g * 64 + oc) * 64) + ic) * 9 + k9]);
    return;
  }
  idx -= 294912;
  if (idx < 51200) {  // relq[t][c] = relative[c][t], t<1600 (pad 0)
    int t = idx >> 5, c = idx & 31;
    relq[idx] = (t < 1567) ? f2bf(rel[c * 1567 + t]) : (u16)0;
    return;
  }
  idx -= 51200;
  if (idx < 51200) {
    int t = idx >> 5, c = idx & 31;
    relk[idx] = (t < 1567) ? f2bf(rel[(32 + c) * 1567 + t]) : (u16)0;
    return;
  }
  idx -= 51200;
  if (idx < 102400) {  // relv[c][t] (c<64, t<1600 pad 0)
    int c = idx / 1600, t = idx % 1600;
    relv[idx] = (t < 1567) ? f2bf(rel[(64 + c) * 1567 + t]) : (u16)0;
    return;
  }
}

__device__ void body_transpose(int bx, int by, int bz, const float* __restrict__ x,
                               u16* __restrict__ xT, char* smem) {
  const int b = bz, c0 = by * 64, n0 = bx * 32;
  const int tid = threadIdx.x;
  u16(*tl)[36] = reinterpret_cast<u16(*)[36]>(smem);
#pragma unroll
  for (int h = 0; h < 2; ++h) {
    int cl = (tid >> 3) + h * 32;
    int n4 = (tid & 7) * 4;
    float4 v = {0.f, 0.f, 0.f, 0.f};
    if (n0 + n4 + 3 < 784)
      v = *reinterpret_cast<const float4*>(x + ((size_t)b * 512 + c0 + cl) * 784 + n0 + n4);
    u32 lo = (u32)f2bf(v.x) | ((u32)f2bf(v.y) << 16);
    u32 hi = (u32)f2bf(v.z) | ((u32)f2bf(v.w) << 16);
    *reinterpret_cast<int2*>(&tl[cl][n4]) = make_int2((int)lo, (int)hi);
  }
  __syncthreads();
  int nl = tid >> 3, c8 = (tid & 7) * 8;
  if (n0 + nl < 784) {
    u16 h[8];
#pragma unroll
    for (int e = 0; e < 8; ++e) h[e] = tl[c8 + e][nl];
    *reinterpret_cast<int4*>(xT + ((size_t)b * 784 + n0 + nl) * 512 + c0 + c8) =
        __builtin_bit_cast(int4, pack8(h));
  }
}

__device__ void body_qkv(int bx, int by, int bz,
                         const u16* __restrict__ W, const u16* __restrict__ xT,
                         const float* __restrict__ gq, const float* __restrict__ bq,
                         u16* __restrict__ Qs, u16* __restrict__ Ks,
                         u16* __restrict__ Vs, char* smem) {
  const int b = bz, mt = by, n0 = bx * 112;
  const int tid = threadIdx.x, lane = tid & 63, wave = tid >> 6;
  const int lm = lane & 15, lq = lane >> 4;
  u16* Bl = reinterpret_cast<u16*>(smem);
  f32x4 zf = {0.f, 0.f, 0.f, 0.f};
  f32x4 acc[7];
#pragma unroll
  for (int t = 0; t < 7; ++t) acc[t] = zf;
  const u16* Bb = xT + ((size_t)b * 784 + n0) * 512;
  const u16* Ar = W + (size_t)(mt * 64 + wave * 16 + lm) * 512;
  const int row0 = tid >> 2, seg8 = (tid & 3) * 8;
  const u16* src0 = Bb + (size_t)row0 * 512 + seg8;
  const u16* src1 = src0 + (size_t)64 * 512;
  u16* dst0 = &Bl[row0 * 40 + seg8];
  u16* dst1 = &Bl[(row0 + 64) * 40 + seg8];
  int4 p0 = *reinterpret_cast<const int4*>(src0);
  int4 p1;
  if (tid < 192) p1 = *reinterpret_cast<const int4*>(src1);
  bf16x8 afc = ld_bf8(Ar + lq * 8);
  for (int ks = 0; ks < 16; ++ks) {
    *reinterpret_cast<int4*>(dst0) = p0;
    if (tid < 192) *reinterpret_cast<int4*>(dst1) = p1;
    __syncthreads();
    bf16x8 af = afc;
    if (ks < 15) {
      p0 = *reinterpret_cast<const int4*>(src0 + (ks + 1) * 32);
      if (tid < 192) p1 = *reinterpret_cast<const int4*>(src1 + (ks + 1) * 32);
      afc = ld_bf8(Ar + (ks + 1) * 32 + lq * 8);
    }
#pragma unroll
    for (int t = 0; t < 7; ++t) {
      bf16x8 bf8 = ld_bf8(&Bl[(t * 16 + lm) * 40 + lq * 8]);
      acc[t] = MFMA16(af, bf8, acc[t]);
    }
    __syncthreads();
  }
  const int og = mt * 64 + wave * 16 + lq * 4;
  float sc[4], bi[4];
#pragma unroll
  for (int r = 0; r < 4; ++r) { sc[r] = gq[og + r] * INVS; bi[r] = bq[og + r]; }
  const int g = og >> 7, r128 = og & 127;
  const size_t bg = (size_t)b * 8 + g;
#pragma unroll
  for (int t = 0; t < 7; ++t) {
    int j = n0 + t * 16 + lm;
    u16 h[4];
#pragma unroll
    for (int r = 0; r < 4; ++r) h[r] = f2bf(acc[t][r] * sc[r] + bi[r]);
    if (r128 < 64) {
      u16* dst = (r128 < 32) ? Qs : Ks;
      int c = r128 & 31;
      u32 lo = (u32)h[0] | ((u32)h[1] << 16);
      u32 hi = (u32)h[2] | ((u32)h[3] << 16);
      *reinterpret_cast<int2*>(dst + (bg * 784 + j) * 32 + c) = make_int2((int)lo, (int)hi);
    } else {
      int c = r128 - 64;
#pragma unroll
      for (int r = 0; r < 4; ++r) Vs[(bg * 64 + c + r) * 784 + j] = h[r];
    }
  }
}

__device__ void body_conv1(int bx, int by, int bz, const u16* __restrict__ xT,
                           const u16* __restrict__ W1t, u16* __restrict__ umid,
                           char* smem) {
  const int b = bz, g = by, n0 = bx * 112;
  const int tid = threadIdx.x, lane = tid & 63, wave = tid >> 6;
  const int lm = lane & 15, lq = lane >> 4;
  u16* xl = reinterpret_cast<u16*>(smem);  // 170*72
  for (int u = tid; u < 1360; u += 256) {
    int row = u >> 3, seg = u & 7;
    int ng = n0 - 29 + row;
    int4 v = {0, 0, 0, 0};
    if (ng >= 0 && ng < 784)
      v = *reinterpret_cast<const int4*>(xT + ((size_t)b * 784 + ng) * 512 + g * 64 + seg * 8);
    *reinterpret_cast<int4*>(&xl[row * 72 + seg * 8]) = v;
  }
  __syncthreads();
  f32x4 zf = {0.f, 0.f, 0.f, 0.f};
  f32x4 acc[7];
#pragma unroll
  for (int t = 0; t < 7; ++t) acc[t] = zf;
  const u16* Wg = W1t + (size_t)g * 9 * 4096;
#pragma unroll
  for (int k9 = 0; k9 < 9; ++k9) {
    const int dh = k9 / 3 - 1, dw = k9 % 3 - 1;
#pragma unroll
    for (int ks = 0; ks < 2; ++ks) {
      bf16x8 af = ld_bf8(Wg + (k9 * 64 + wave * 16 + lm) * 64 + ks * 32 + lq * 8);
#pragma unroll
      for (int t = 0; t < 7; ++t) {
        int n = n0 + t * 16 + lm;
        int ww = n % 28 + dw;
        bf16x8 bf8;
        if (ww >= 0 && ww < 28)
          bf8 = ld_bf8(&xl[(t * 16 + lm + dh * 28 + dw + 29) * 72 + ks * 32 + lq * 8]);
        else
          bf8 = zero8();
        acc[t] = MFMA16(af, bf8, acc[t]);
      }
    }
  }
  const int oc4 = g * 64 + wave * 16 + lq * 4;
#pragma unroll
  for (int t = 0; t < 7; ++t) {
    int j = n0 + t * 16 + lm;
    u16 h[4];
#pragma unroll
    for (int r = 0; r < 4; ++r) h[r] = f2bf(acc[t][r]);
    u32 lo = (u32)h[0] | ((u32)h[1] << 16);
    u32 hi = (u32)h[2] | ((u32)h[3] << 16);
    *reinterpret_cast<int2*>(umid + ((size_t)b * 784 + j) * 512 + oc4) = make_int2((int)lo, (int)hi);
  }
}

// simple staging (no prefetch) to keep VGPR low — fused with attn in k_ax.
// Writes unT (f32, for pw) and unTh (bf16 relu, for rw).
__device__ void body_x2(int bx, int by, int bz,
                        const u16* __restrict__ W, const u16* __restrict__ Bsrc,
                        const float* __restrict__ gv, const float* __restrict__ bv,
                        float* __restrict__ outT, u16* __restrict__ outTh, char* smem) {
  const int b = bz, mt = by, n0 = bx * 112;
  const int tid = threadIdx.x, lane = tid & 63, wave = tid >> 6;
  const int lm = lane & 15, lq = lane >> 4;
  u16* Bl = reinterpret_cast<u16*>(smem);
  f32x4 zf = {0.f, 0.f, 0.f, 0.f};
  f32x4 acc[7];
#pragma unroll
  for (int t = 0; t < 7; ++t) acc[t] = zf;
  const u16* Bb = Bsrc + ((size_t)b * 784 + n0) * 512;
  const u16* Ar = W + (size_t)(mt * 64 + wave * 16 + lm) * 512;
  for (int ks = 0; ks < 16; ++ks) {
    __syncthreads();
    for (int u = tid; u < 448; u += 256) {
      int row = u >> 2, seg = u & 3;
      int4 v = *reinterpret_cast<const int4*>(Bb + (size_t)row * 512 + ks * 32 + seg * 8);
      *reinterpret_cast<int4*>(&Bl[row * 40 + seg * 8]) = v;
    }
    __syncthreads();
    bf16x8 af = ld_bf8(Ar + ks * 32 + lq * 8);
#pragma unroll
    for (int t = 0; t < 7; ++t) {
      bf16x8 bf8 = ld_bf8(&Bl[(t * 16 + lm) * 40 + lq * 8]);
      acc[t] = MFMA16(af, bf8, acc[t]);
    }
  }
  const int og = mt * 64 + wave * 16 + lq * 4;
  float sc[4], bi[4];
#pragma unroll
  for (int r = 0; r < 4; ++r) { sc[r] = gv[og + r] * INVS; bi[r] = bv[og + r]; }
#pragma unroll
  for (int t = 0; t < 7; ++t) {
    int j = n0 + t * 16 + lm;
    float4 o4;
    o4.x = acc[t][0] * sc[0] + bi[0];
    o4.y = acc[t][1] * sc[1] + bi[1];
    o4.z = acc[t][2] * sc[2] + bi[2];
    o4.w = acc[t][3] * sc[3] + bi[3];
    *reinterpret_cast<float4*>(outT + ((size_t)b * 784 + j) * 512 + og) = o4;
    u32 lo = (u32)f2bf(fmaxf(o4.x, 0.f)) | ((u32)f2bf(fmaxf(o4.y, 0.f)) << 16);
    u32 hi = (u32)f2bf(fmaxf(o4.z, 0.f)) | ((u32)f2bf(fmaxf(o4.w, 0.f)) << 16);
    *reinterpret_cast<int2*>(outTh + ((size_t)b * 784 + j) * 512 + og) = make_int2((int)lo, (int)hi);
  }
}

// attn smem layout (bytes): Pl u16[16+16*872] @0 (27936), KRs f32[4*16*34] @27936
// (8704), WM f32[64] @36640 (256), rstat f32[16] @36896 (64). Total 36960.
__device__ void body_attn(int bx, int by, int bz,
                          const u16* __restrict__ Qs, const u16* __restrict__ Ks,
                          const u16* __restrict__ Vs, const u16* __restrict__ relq,
                          const u16* __restrict__ relk, const u16* __restrict__ relv,
                          const float* __restrict__ g_sim, const float* __restrict__ g_out,
                          const float* __restrict__ b_out, float* __restrict__ binT,
                          u16* __restrict__ binTh, char* smem) {
  const int b = bz, g = by, i0 = bx * 16;
  const int tid = threadIdx.x, lane = tid & 63, wave = tid >> 6;
  const int lm = lane & 15, lq = lane >> 4;
  u16* Pl = reinterpret_cast<u16*>(smem);
  float* KRs = reinterpret_cast<float*>(smem + 27936);  // [w][m][c34] -> (w*16+m)*34+c
  float* WM = reinterpret_cast<float*>(smem + 36640);   // [w][row] -> w*16+row
  float* rstat = reinterpret_cast<float*>(smem + 36896);
  // zero header [0,16) and right pads [784,872) of each row
  for (int u = tid; u < 1424; u += 256) {
    int idx = (u < 16) ? u : (16 + ((u - 16) / 88) * 872 + 784 + (u - 16) % 88);
    Pl[idx] = 0;
  }
  const float s0 = g_sim[g] * INVS, s1 = g_sim[8 + g] * INVS, s2 = g_sim[16 + g] * INVS;
  const size_t bg = (size_t)b * 8 + g;
  const u16* Qb = Qs + bg * 784 * 32;
  const u16* Kb = Ks + bg * 784 * 32;
  const u16* Vb = Vs + bg * 64 * 784;
  const bf16x8 aq = ld_bf8(Qb + (i0 + lm) * 32 + lq * 8);
  const f32x4 zf = {0.f, 0.f, 0.f, 0.f};
  // ---- phase 1: logits -> fp16 LDS; wave owns j-tiles wave, wave+4, ... ----
  float vmax[4] = {-1e30f, -1e30f, -1e30f, -1e30f};
  bf16x8 kfc, bq0c, bq1c, bk0c, bk1c;
  {
    const int j0 = wave * 16;
    const int d0 = 768 + i0 - j0, e0 = 768 + j0 - i0;
    kfc = ld_bf8(Kb + (j0 + lm) * 32 + lq * 8);
    bq0c = ld_bf8(relq + (d0 + lm) * 32 + lq * 8);
    bq1c = ld_bf8(relq + (d0 + 16 + lm) * 32 + lq * 8);
    bk0c = ld_bf8(relk + (e0 + lm) * 32 + lq * 8);
    bk1c = ld_bf8(relk + (e0 + 16 + lm) * 32 + lq * 8);
  }
  int jt = wave;
  for (int rr = 0; rr < 13; ++rr) {
    const int jtn = jt + 4;
    bf16x8 kfn = kfc, bq0n = bq0c, bq1n = bq1c, bk0n = bk0c, bk1n = bk1c;
    if (jtn < 49) {
      const int j0n = jtn * 16;
      const int d0 = 768 + i0 - j0n, e0 = 768 + j0n - i0;
      kfn = ld_bf8(Kb + (j0n + lm) * 32 + lq * 8);
      bq0n = ld_bf8(relq + (d0 + lm) * 32 + lq * 8);
      bq1n = ld_bf8(relq + (d0 + 16 + lm) * 32 + lq * 8);
      bk0n = ld_bf8(relk + (e0 + lm) * 32 + lq * 8);
      bk1n = ld_bf8(relk + (e0 + 16 + lm) * 32 + lq * 8);
    }
    if (jt < 49) {
      const int j0 = jt * 16;
      f32x4 aqk = MFMA16(aq, kfc, zf);      // qk[i][j]
      f32x4 q0 = MFMA16(aq, bq0c, zf);      // QRt[i][d] cols 0..15
      f32x4 q1 = MFMA16(aq, bq1c, zf);      // cols 16..31
      f32x4 k0 = MFMA16(kfc, bk0c, zf);     // KRt[j][s] cols 0..15
      f32x4 k1 = MFMA16(kfc, bk1c, zf);
#pragma unroll
      for (int r = 0; r < 4; ++r) {
        int m = lq * 4 + r;
        KRs[(wave * 16 + m) * 34 + lm] = k0[r];
        KRs[(wave * 16 + m) * 34 + 16 + lm] = k1[r];
      }
      // per-wave LDS RAW: compiler inserts lgkmcnt wait, no barrier needed
#pragma unroll
      for (int r = 0; r < 4; ++r) {
        int m = lq * 4 + r, n = lm;
        int c = m - n + 15;  // qr gather col
        int srcl = (c & 15) | (lane & 48);
        float t0 = bpermf(q0[r], srcl), t1 = bpermf(q1[r], srcl);
        float qv = (c & 16) ? t1 : t0;
        float kv = KRs[(wave * 16 + n) * 34 + (n - m + 15)];
        float val = aqk[r] * s0 + qv * s1 + kv * s2;  // b_sim drops (shift-invariant)
        vmax[r] = fmaxf(vmax[r], val);
        _Float16 hv = (_Float16)val;
        Pl[16 + m * 872 + j0 + n] = __builtin_bit_cast(u16, hv);
      }
    }
    jt = jtn;
    kfc = kfn; bq0c = bq0n; bq1c = bq1n; bk0c = bk0n; bk1c = bk1n;
  }
  // wave-local row max reduce over n (lm bits)
#pragma unroll
  for (int r = 0; r < 4; ++r) {
#pragma unroll
    for (int d = 1; d < 16; d <<= 1) vmax[r] = fmaxf(vmax[r], __shfl_xor(vmax[r], d, 64));
  }
  if (lm == 0) {
#pragma unroll
    for (int r = 0; r < 4; ++r) WM[wave * 16 + lq * 4 + r] = vmax[r];
  }
  __syncthreads();
  // ---- phase 2: softmax, fp16 -> bf16 P~ IN-PLACE (same index, same size) ----
  {
    const int row = tid >> 4, sub = tid & 15;
    u16* Pr = &Pl[16 + row * 872];
    float gmax = fmaxf(fmaxf(WM[row], WM[16 + row]), fmaxf(WM[32 + row], WM[48 + row]));
    float sm = 0.f;
    for (int k = 0; k < 49; ++k) {
      int j = sub + 16 * k;
      _Float16 hv = __builtin_bit_cast(_Float16, Pr[j]);
      float e = __expf((float)hv - gmax);
      sm += e;
      Pr[j] = f2bf(e);
    }
#pragma unroll
    for (int d = 1; d < 16; d <<= 1) sm += __shfl_xor(sm, d, 64);
    if (sub == 0) rstat[row] = 1.0f / sm;
  }
  __syncthreads();
  // ---- phase 3: PV; wave = c-chunk of 16; sv = P~ @ V^T, sve = Psh @ relv^T ----
  f32x4 accV = zf, accE = zf;
  const int coff = wave * 16;
  const u16* Vr = Vb + (size_t)(coff + lm) * 784;
  const u16* Rr = relv + (size_t)(coff + lm) * 1600 + i0;
  const u16* Prow = &Pl[16 + lm * 872];
  for (int ks = 0; ks < 25; ++ks) {
    bf16x8 ap = ld_bf8(Prow + ks * 32 + lq * 8);  // cols>=784 read zero pad
    bf16x8 bv = ld_bf8(Vr + ks * 32 + lq * 8);
    accV = MFMA16(ap, bv, accV);
    const int base = 783 + lm - ks * 32 - lq * 8;  // Psh gather; pads/header give 0
    u16 h[8];
#pragma unroll
    for (int e = 0; e < 8; ++e) h[e] = Prow[base - e];
    bf16x8 ash = pack8(h);
    bf16x8 br = ld_bf8(Rr + ks * 32 + lq * 8);
    accE = MFMA16(ash, br, accE);
  }
  // ---- epilogue: binary = bn(sv)+bn(sve); write f32 (for pw) + bf16 relu (for rw) ----
  const int c = coff + lm;
  const int oi = g * 128 + 2 * c;
  const float so0 = g_out[oi] * INVS, bo0 = b_out[oi];
  const float so1 = g_out[oi + 1] * INVS, bo1 = b_out[oi + 1];
#pragma unroll
  for (int r = 0; r < 4; ++r) {
    int row = lq * 4 + r;
    float rl = rstat[row];
    float val = accV[r] * rl * so0 + bo0 + accE[r] * rl * so1 + bo1;
    size_t ofs = ((size_t)b * 784 + i0 + row) * 512 + g * 64 + c;
    binT[ofs] = val;
    binTh[ofs] = f2bf(fmaxf(val, 0.f));
  }
}

// ================= fused kernels =================

// prep (8096 blocks) ∥ transpose (1600 blocks)
__global__ __launch_bounds__(256) void k_pt(
    const float* __restrict__ x, u16* __restrict__ xT,
    const float* __restrict__ qkv_w, const float* __restrict__ xw2,
    const float* __restrict__ rw, const float* __restrict__ pw,
    const float* __restrict__ xw1, const float* __restrict__ rel,
    u16* __restrict__ Wq, u16* __restrict__ W2, u16* __restrict__ Wr,
    u16* __restrict__ Wp, u16* __restrict__ W1t, u16* __restrict__ relq,
    u16* __restrict__ relk, u16* __restrict__ relv) {
  __shared__ __align__(16) char smem[4608];
  const int bid = blockIdx.x;
  if (bid < 1600) {
    body_transpose(bid % 25, (bid / 25) % 8, bid / 200, x, xT, smem);
  } else {
    body_prep((bid - 1600) * 256 + threadIdx.x, qkv_w, xw2, rw, pw, xw1, rel,
              Wq, W2, Wr, Wp, W1t, relq, relk, relv);
  }
}

// conv1 (448 blocks) ∥ qkv (896 blocks)
__global__ __launch_bounds__(256) void k_qc(
    const u16* __restrict__ Wq, const u16* __restrict__ xT,
    const float* __restrict__ gq, const float* __restrict__ bq,
    u16* __restrict__ Qs, u16* __restrict__ Ks, u16* __restrict__ Vs,
    const u16* __restrict__ W1t, u16* __restrict__ umid) {
  __shared__ __align__(16) char smem[24480];
  const int bid = blockIdx.x;
  if (bid < 448) {
    body_conv1(bid % 7, (bid / 7) % 8, bid / 56, xT, W1t, umid, smem);
  } else {
    const int q = bid - 448;
    body_qkv(q % 7, (q / 7) % 16, q / 112, Wq, xT, gq, bq, Qs, Ks, Vs, smem);
  }
}

// x2 (448 blocks) ∥ attn (3136 blocks)
__global__ __launch_bounds__(256) void k_ax(
    const u16* __restrict__ W2, const u16* __restrict__ umid,
    const float* __restrict__ g_x, const float* __restrict__ b_x,
    float* __restrict__ unT, u16* __restrict__ unTh,
    const u16* __restrict__ Qs, const u16* __restrict__ Ks, const u16* __restrict__ Vs,
    const u16* __restrict__ relq, const u16* __restrict__ relk,
    const u16* __restrict__ relv, const float* __restrict__ g_sim,
    const float* __restrict__ g_out, const float* __restrict__ b_out,
    float* __restrict__ binT, u16* __restrict__ binTh) {
  __shared__ __align__(16) char smem[36960];
  const int bid = blockIdx.x;
  if (bid < 448) {
    body_x2(bid % 7, (bid / 7) % 8, bid / 56, W2, umid, g_x, b_x, unT, unTh, smem);
  } else {
    const int a = bid - 448;
    body_attn(a % 49, (a / 49) % 8, a / 392, Qs, Ks, Vs, relq, relk, relv,
              g_sim, g_out, b_out, binT, binTh, smem);
  }
}

// ---------------- rw GEMM (pure bf16): r = relu(bn(Wr @ [unTh|binTh])) -> rT ----------------
__global__ __launch_bounds__(256) void k_gemm_rw(
    const u16* __restrict__ W, const u16* __restrict__ unTh, const u16* __restrict__ binTh,
    const float* __restrict__ gv, const float* __restrict__ bv, u16* __restrict__ rT) {
  const int b = blockIdx.z, mt = blockIdx.y, n0 = blockIdx.x * 112;
  const int tid = threadIdx.x, lane = tid & 63, wave = tid >> 6;
  const int lm = lane & 15, lq = lane >> 4;
  __shared__ __align__(16) u16 Bl[112 * 40];
  f32x4 zf = {0.f, 0.f, 0.f, 0.f};
  f32x4 acc[7];
#pragma unroll
  for (int t = 0; t < 7; ++t) acc[t] = zf;
  const u16* Ar = W + (size_t)(mt * 64 + wave * 16 + lm) * 1024;
  const int row0 = tid >> 2, seg8 = (tid & 3) * 8;
  const size_t off0 = ((size_t)b * 784 + n0 + row0) * 512 + seg8;
  const size_t off1 = off0 + (size_t)64 * 512;
  u16* dst0 = &Bl[row0 * 40 + seg8];
  u16* dst1 = &Bl[(row0 + 64) * 40 + seg8];
  int4 p0 = *reinterpret_cast<const int4*>(unTh + off0);
  int4 p1;
  if (tid < 192) p1 = *reinterpret_cast<const int4*>(unTh + off1);
  bf16x8 afc = ld_bf8(Ar + lq * 8);
  for (int ks = 0; ks < 32; ++ks) {
    *reinterpret_cast<int4*>(dst0) = p0;
    if (tid < 192) *reinterpret_cast<int4*>(dst1) = p1;
    __syncthreads();
    bf16x8 af = afc;
    if (ks < 31) {
      const int ksn = ks + 1;
      const u16* sb = (ksn < 16) ? unTh : binTh;
      const int k0 = (ksn & 15) * 32;
      p0 = *reinterpret_cast<const int4*>(sb + off0 + k0);
      if (tid < 192) p1 = *reinterpret_cast<const int4*>(sb + off1 + k0);
      afc = ld_bf8(Ar + ksn * 32 + lq * 8);
    }
#pragma unroll
    for (int t = 0; t < 7; ++t) {
      bf16x8 bf8 = ld_bf8(&Bl[(t * 16 + lm) * 40 + lq * 8]);
      acc[t] = MFMA16(af, bf8, acc[t]);
    }
    __syncthreads();
  }
  const int og = mt * 64 + wave * 16 + lq * 4;
  float sc[4], bi[4];
#pragma unroll
  for (int r = 0; r < 4; ++r) { sc[r] = gv[og + r] * INVS; bi[r] = bv[og + r]; }
#pragma unroll
  for (int t = 0; t < 7; ++t) {
    int j = n0 + t * 16 + lm;
    u16 h[4];
#pragma unroll
    for (int r = 0; r < 4; ++r) h[r] = f2bf(fmaxf(acc[t][r] * sc[r] + bi[r], 0.f));
    u32 lo = (u32)h[0] | ((u32)h[1] << 16);
    u32 hi = (u32)h[2] | ((u32)h[3] << 16);
    *reinterpret_cast<int2*>(rT + ((size_t)b * 784 + j) * 512 + og) = make_int2((int)lo, (int)hi);
  }
}

// ---------------- pw GEMM + sigmoid gate + final fuse -> d_out ----------------
__global__ __launch_bounds__(256) void k_gemm_pw(
    const u16* __restrict__ W, const u16* __restrict__ rT,
    const float* __restrict__ gv, const float* __restrict__ bv,
    const float* __restrict__ binT, const float* __restrict__ unT,
    float* __restrict__ out) {
  const int b = blockIdx.z, mt = blockIdx.y, n0 = blockIdx.x * 112;
  const int tid = threadIdx.x, lane = tid & 63, wave = tid >> 6;
  const int lm = lane & 15, lq = lane >> 4;
  __shared__ __align__(16) u16 Bl[112 * 40];
  f32x4 zf = {0.f, 0.f, 0.f, 0.f};
  f32x4 acc[7];
#pragma unroll
  for (int t = 0; t < 7; ++t) acc[t] = zf;
  const u16* Bb = rT + ((size_t)b * 784 + n0) * 512;
  const u16* Ar = W + (size_t)(mt * 64 + wave * 16 + lm) * 512;
  const int row0 = tid >> 2, seg8 = (tid & 3) * 8;
  const u16* src0 = Bb + (size_t)row0 * 512 + seg8;
  const u16* src1 = src0 + (size_t)64 * 512;
  u16* dst0 = &Bl[row0 * 40 + seg8];
  u16* dst1 = &Bl[(row0 + 64) * 40 + seg8];
  int4 p0 = *reinterpret_cast<const int4*>(src0);
  int4 p1;
  if (tid < 192) p1 = *reinterpret_cast<const int4*>(src1);
  bf16x8 afc = ld_bf8(Ar + lq * 8);
  for (int ks = 0; ks < 16; ++ks) {
    *reinterpret_cast<int4*>(dst0) = p0;
    if (tid < 192) *reinterpret_cast<int4*>(dst1) = p1;
    __syncthreads();
    bf16x8 af = afc;
    if (ks < 15) {
      p0 = *reinterpret_cast<const int4*>(src0 + (ks + 1) * 32);
      if (tid < 192) p1 = *reinterpret_cast<const int4*>(src1 + (ks + 1) * 32);
      afc = ld_bf8(Ar + (ks + 1) * 32 + lq * 8);
    }
#pragma unroll
    for (int t = 0; t < 7; ++t) {
      bf16x8 bf8 = ld_bf8(&Bl[(t * 16 + lm) * 40 + lq * 8]);
      acc[t] = MFMA16(af, bf8, acc[t]);
    }
    __syncthreads();
  }
  const int og = mt * 64 + wave * 16 + lq * 4;
  float sc[4], bi[4];
#pragma unroll
  for (int r = 0; r < 4; ++r) { sc[r] = gv[og + r] * INVS; bi[r] = bv[og + r]; }
#pragma unroll
  for (int t = 0; t < 7; ++t) {
    int j = n0 + t * 16 + lm;
    float4 bin4 = *reinterpret_cast<const float4*>(binT + ((size_t)b * 784 + j) * 512 + og);
    float4 un4 = *reinterpret_cast<const float4*>(unT + ((size_t)b * 784 + j) * 512 + og);
    float binv[4] = {bin4.x, bin4.y, bin4.z, bin4.w};
    float unv[4] = {un4.x, un4.y, un4.z, un4.w};
#pragma unroll
    for (int r = 0; r < 4; ++r) {
      float gt = 1.f / (1.f + __expf(-(acc[t][r] * sc[r] + bi[r])));
      out[((size_t)b * 512 + og + r) * 784 + j] = gt * binv[r] + unv[r];
    }
  }
}

extern "C" void kernel_launch(void* const* d_in, const int* in_sizes, int n_in,
                              void* d_out, int out_size, void* d_ws, size_t ws_size,
                              hipStream_t stream) {
  const float* x = (const float*)d_in[0];
  const float* qkv_w = (const float*)d_in[1];
  const float* g_qkv = (const float*)d_in[2];
  const float* b_qkv = (const float*)d_in[3];
  const float* g_sim = (const float*)d_in[4];
  // d_in[5] = b_sim: unused (softmax is shift-invariant per (b,g) row)
  const float* g_out = (const float*)d_in[6];
  const float* b_out = (const float*)d_in[7];
  const float* relative = (const float*)d_in[8];
  const float* xw1 = (const float*)d_in[9];
  const float* xw2 = (const float*)d_in[10];
  const float* g_x = (const float*)d_in[11];
  const float* b_x = (const float*)d_in[12];
  const float* rw = (const float*)d_in[13];
  const float* g_r = (const float*)d_in[14];
  const float* b_r = (const float*)d_in[15];
  const float* pw = (const float*)d_in[16];
  const float* g_p = (const float*)d_in[17];
  const float* b_p = (const float*)d_in[18];

  char* p = (char*)d_ws;
  auto take = [&](size_t n) { char* q = p; p += (n + 255) & ~(size_t)255; return q; };
  u16* xT = (u16*)take((size_t)8 * 784 * 512 * 2);
  u16* Wq = (u16*)take((size_t)1024 * 512 * 2);
  u16* W2 = (u16*)take((size_t)512 * 512 * 2);
  u16* Wr = (u16*)take((size_t)512 * 1024 * 2);
  u16* Wp = (u16*)take((size_t)512 * 512 * 2);
  u16* W1t = (u16*)take((size_t)294912 * 2);
  u16* relq = (u16*)take((size_t)51200 * 2);
  u16* relk = (u16*)take((size_t)51200 * 2);
  u16* relv = (u16*)take((size_t)102400 * 2);
  u16* Qs = (u16*)take((size_t)8 * 8 * 784 * 32 * 2);
  u16* Ks = (u16*)take((size_t)8 * 8 * 784 * 32 * 2);
  u16* Vs = (u16*)take(((size_t)8 * 8 * 64 * 784 + 64) * 2);  // +64 pad for K=800 reads
  u16* umid = (u16*)take((size_t)8 * 784 * 512 * 2);
  float* unT = (float*)take((size_t)8 * 784 * 512 * 4);
  float* binT = (float*)take((size_t)8 * 784 * 512 * 4);
  u16* rT = (u16*)take((size_t)8 * 784 * 512 * 2);
  u16* unTh = (u16*)take((size_t)8 * 784 * 512 * 2);
  u16* binTh = (u16*)take((size_t)8 * 784 * 512 * 2);

  k_pt<<<dim3(9696), dim3(256), 0, stream>>>(x, xT, qkv_w, xw2, rw, pw, xw1, relative,
                                             Wq, W2, Wr, Wp, W1t, relq, relk, relv);
  k_qc<<<dim3(1344), dim3(256), 0, stream>>>(Wq, xT, g_qkv, b_qkv, Qs, Ks, Vs, W1t, umid);
  k_ax<<<dim3(3584), dim3(256), 0, stream>>>(W2, umid, g_x, b_x, unT, unTh, Qs, Ks, Vs,
                                             relq, relk, relv, g_sim, g_out, b_out,
                                             binT, binTh);
  k_gemm_rw<<<dim3(7, 8, 8), dim3(256), 0, stream>>>(Wr, unTh, binTh, g_r, b_r, rT);
  k_gemm_pw<<<dim3(7, 8, 8), dim3(256), 0, stream>>>(Wp, rT, g_p, b_p, binT, unT,
                                                     (float*)d_out);
}